// Round 9
// baseline (247.034 us; speedup 1.0000x reference)
//
#include <hip/hip_runtime.h>
#include <hip/hip_bf16.h>
#include <cstdint>

#define DM 1024
#define DFF 4096
#define NB 2
#define TT 2048
#define NH 16
#define DH 64

typedef unsigned short u16;
typedef __bf16 bf16x8 __attribute__((ext_vector_type(8)));
typedef float f32x4 __attribute__((ext_vector_type(4)));

__device__ __forceinline__ u16 f2b(float f) {
    union { float f; unsigned u; } v; v.f = f;
    unsigned u = v.u;
    return (u16)((u + 0x7FFFu + ((u >> 16) & 1u)) >> 16);
}

__device__ __forceinline__ float b2f(u16 u) {
    union { unsigned x; float f; } v;
    v.x = ((unsigned)u) << 16;
    return v.f;
}

__device__ __forceinline__ unsigned cvtpk(float a, float b) {
    unsigned r;
    asm("v_cvt_pk_bf16_f32 %0, %1, %2" : "=v"(r) : "v"(a), "v"(b));
    return r;
}

// gelu(z) = z * sigmoid(2*0.79788456*(z+0.044715 z^3)); exp2-based, ~7 VALU ops.
__device__ __forceinline__ float gelu_fast(float z) {
    const float u = z * z;
    const float w = z * __builtin_fmaf(u, 0.10294324f, 2.3022082f);
    const float e = exp2f(w);
    const float r = __builtin_amdgcn_rcpf(1.0f + e);
    return z - z * r;
}

__device__ __forceinline__ f32x4 mfma_bf16(bf16x8 a, bf16x8 b, f32x4 c) {
    return __builtin_amdgcn_mfma_f32_16x16x32_bf16(a, b, c, 0, 0, 0);
}

__device__ __forceinline__ void gload_lds16(const void* g, void* l) {
    __builtin_amdgcn_global_load_lds((const __attribute__((address_space(1))) unsigned int*)g,
                                     (__attribute__((address_space(3))) unsigned int*)l, 16, 0, 0);
}

// ---------------- transpose + fp32->bf16 convert: Wt[n][k] = bf16(W[k][n]) ----------------
__global__ __launch_bounds__(256) void transW(const float* __restrict__ W, u16* __restrict__ Wt,
                                              int K, int N) {
    __shared__ float t[32][33];
    int tx = threadIdx.x & 31, ty = threadIdx.x >> 5;
    int k0 = blockIdx.y * 32, n0 = blockIdx.x * 32;
#pragma unroll
    for (int j = 0; j < 4; ++j)
        t[ty + 8 * j][tx] = W[(size_t)(k0 + ty + 8 * j) * N + n0 + tx];
    __syncthreads();
#pragma unroll
    for (int j = 0; j < 4; ++j)
        Wt[(size_t)(n0 + ty + 8 * j) * K + k0 + tx] = f2b(t[tx][ty + 8 * j]);
}

// ---------------- LayerNorm fp32 -> bf16 ----------------
__global__ __launch_bounds__(256) void ln_kernel(const float* __restrict__ X,
                                                 const float* __restrict__ g,
                                                 const float* __restrict__ bt,
                                                 u16* __restrict__ H) {
    int row = blockIdx.x, tid = threadIdx.x;
    float4 v = ((const float4*)(X + (size_t)row * DM))[tid];
    float s = v.x + v.y + v.z + v.w;
    float ss = v.x * v.x + v.y * v.y + v.z * v.z + v.w * v.w;
#pragma unroll
    for (int off = 32; off >= 1; off >>= 1) {
        s += __shfl_xor(s, off);
        ss += __shfl_xor(ss, off);
    }
    __shared__ float sb[8];
    int w = tid >> 6, lane = tid & 63;
    if (lane == 0) { sb[w] = s; sb[4 + w] = ss; }
    __syncthreads();
    s = sb[0] + sb[1] + sb[2] + sb[3];
    ss = sb[4] + sb[5] + sb[6] + sb[7];
    float mu = s * (1.0f / DM);
    float var = ss * (1.0f / DM) - mu * mu;
    float rstd = rsqrtf(var + 1e-5f);
    float4 gv = ((const float4*)g)[tid];
    float4 bv = ((const float4*)bt)[tid];
    uint2 hv;
    hv.x = cvtpk((v.x - mu) * rstd * gv.x + bv.x, (v.y - mu) * rstd * gv.y + bv.y);
    hv.y = cvtpk((v.z - mu) * rstd * gv.z + bv.z, (v.w - mu) * rstd * gv.w + bv.w);
    ((uint2*)(H + (size_t)row * DM))[tid] = hv;
}

// ---------------- out += p1 + p2 + p3 (bf16 partials) ----------------
__global__ __launch_bounds__(256) void add3_kernel(float* __restrict__ out,
                                                   const u16* __restrict__ p1,
                                                   const u16* __restrict__ p2,
                                                   const u16* __restrict__ p3, int n4) {
    int idx = blockIdx.x * 256 + threadIdx.x;
    const int stride = gridDim.x * 256;
    for (; idx < n4; idx += stride) {
        float4 a = ((const float4*)out)[idx];
        ushort4 b1 = ((const ushort4*)p1)[idx];
        ushort4 b2 = ((const ushort4*)p2)[idx];
        ushort4 b3 = ((const ushort4*)p3)[idx];
        a.x += b2f(b1.x) + b2f(b2.x) + b2f(b3.x);
        a.y += b2f(b1.y) + b2f(b2.y) + b2f(b3.y);
        a.z += b2f(b1.z) + b2f(b2.z) + b2f(b3.z);
        a.w += b2f(b1.w) + b2f(b2.w) + b2f(b3.w);
        ((float4*)out)[idx] = a;
    }
}

// ================= 256x256 8-phase GEMM (T2+T3+T4+T5) =================
// 512 threads = 8 waves (2M x 4N); BK=64; per-wave C = 128x64 (8x4 16x16 frags).
// MODE 0: qkv scatter epilogue; MODE 2: gelu(C+bias) bf16.
template <int MODE>
__global__ __launch_bounds__(512, 2) void gemm256(
    const u16* __restrict__ A, const u16* __restrict__ Bt, int M, int N, int K,
    u16* __restrict__ oq, u16* __restrict__ ok, u16* __restrict__ vt,
    const float* __restrict__ bias, u16* __restrict__ outbf) {
    __shared__ __align__(16) u16 Alds[2][256][64];
    __shared__ __align__(16) u16 Blds[2][256][64];
    const int tid = threadIdx.x;
    const int lane = tid & 63, w = tid >> 6;
    const int wm = w >> 2, wn = w & 3;
    const int l15 = lane & 15, lg = lane >> 4;
    int bid = blockIdx.x + gridDim.x * blockIdx.y;
    const int nwg = gridDim.x * gridDim.y;
    bid = (bid & 7) * (nwg >> 3) + (bid >> 3);
    const int bm = (bid / gridDim.x) * 256, bn = (bid % gridDim.x) * 256;
    const int srow = tid >> 3, pch = tid & 7;
    const int lc = pch ^ (srow & 7);

    const u16* Ap = A + (size_t)(bm + srow) * K + lc * 8;
    const u16* Bp = Bt + (size_t)(bn + srow) * K + lc * 8;

    f32x4 acc[8][4] = {};
    bf16x8 bf[4][2];
    const int NT = K >> 6;  // assumed even, >= 2

#define SA256(buf, t)                                                           \
    {                                                                           \
        _Pragma("unroll") for (int j = 0; j < 4; ++j)                           \
            gload_lds16(Ap + (size_t)(64 * j) * K + (t) * 64,                   \
                        &Alds[buf][srow + 64 * j][pch * 8]);                    \
    }
#define SB256(buf, t)                                                           \
    {                                                                           \
        _Pragma("unroll") for (int j = 0; j < 4; ++j)                           \
            gload_lds16(Bp + (size_t)(64 * j) * K + (t) * 64,                   \
                        &Blds[buf][srow + 64 * j][pch * 8]);                    \
    }

#define PHASE(BUF, P, STAGE, WAIT)                                              \
    {                                                                           \
        bf16x8 af[2][2];                                                        \
        _Pragma("unroll") for (int i = 0; i < 2; ++i) {                         \
            const int row = wm * 128 + (2 * (P) + i) * 16 + l15;                \
            _Pragma("unroll") for (int ks = 0; ks < 2; ++ks)                    \
                af[i][ks] =                                                     \
                    *(const bf16x8*)&Alds[BUF][row][((ks * 4 + lg) ^ (row & 7)) * 8]; \
        }                                                                       \
        if constexpr ((P) == 0) {                                               \
            _Pragma("unroll") for (int nf = 0; nf < 4; ++nf) {                  \
                const int row = wn * 64 + nf * 16 + l15;                        \
                _Pragma("unroll") for (int ks = 0; ks < 2; ++ks)                \
                    bf[nf][ks] =                                                \
                        *(const bf16x8*)&Blds[BUF][row][((ks * 4 + lg) ^ (row & 7)) * 8]; \
            }                                                                   \
        }                                                                       \
        STAGE;                                                                  \
        WAIT;                                                                   \
        __builtin_amdgcn_s_barrier();                                           \
        asm volatile("s_waitcnt lgkmcnt(0)" ::: "memory");                      \
        __builtin_amdgcn_sched_barrier(0);                                      \
        __builtin_amdgcn_s_setprio(1);                                          \
        _Pragma("unroll") for (int i = 0; i < 2; ++i)                           \
            _Pragma("unroll") for (int nf = 0; nf < 4; ++nf)                    \
                _Pragma("unroll") for (int ks = 0; ks < 2; ++ks)                \
                    acc[2 * (P) + i][nf] =                                      \
                        mfma_bf16(af[i][ks], bf[nf][ks], acc[2 * (P) + i][nf]); \
        __builtin_amdgcn_s_setprio(0);                                          \
        __builtin_amdgcn_s_barrier();                                           \
    }

    SB256(0, 0);
    SA256(0, 0);
    SB256(1, 1);
    asm volatile("s_waitcnt vmcnt(4)" ::: "memory");
    __builtin_amdgcn_sched_barrier(0);
    __builtin_amdgcn_s_barrier();

    for (int it = 0; it < (NT >> 1); ++it) {
        const int t0 = 2 * it;
        const bool more = (t0 + 2 < NT);
        PHASE(0, 0, { SA256(1, t0 + 1); }, {});
        PHASE(0, 1, { if (more) SB256(0, t0 + 2); }, {});
        PHASE(0, 2, {}, {});
        PHASE(0, 3, {}, {
            if (more) { asm volatile("s_waitcnt vmcnt(4)" ::: "memory"); }
            else { asm volatile("s_waitcnt vmcnt(0)" ::: "memory"); }
            __builtin_amdgcn_sched_barrier(0);
        });
        PHASE(1, 0, { if (more) SA256(0, t0 + 2); }, {});
        PHASE(1, 1, { if (more) SB256(1, t0 + 3); }, {});
        PHASE(1, 2, {}, {});
        PHASE(1, 3, {}, {
            if (more) {
                asm volatile("s_waitcnt vmcnt(4)" ::: "memory");
                __builtin_amdgcn_sched_barrier(0);
            }
        });
    }
#undef PHASE
#undef SA256
#undef SB256

    const int m0 = bm + wm * 128, n0 = bn + wn * 64;
#pragma unroll
    for (int mi = 0; mi < 8; ++mi) {
#pragma unroll
        for (int ni = 0; ni < 4; ++ni) {
            if constexpr (MODE == 0) {
                const int n = n0 + ni * 16 + l15;
                const int which = n >> 10;
                const int hh = (n >> 6) & 15, d = n & 63;
                const int mbase = m0 + mi * 16 + 4 * lg;
                const int bb = mbase >> 11, t = mbase & 2047;
                if (which == 2) {
                    uint2 pv;
                    pv.x = cvtpk(acc[mi][ni][0], acc[mi][ni][1]);
                    pv.y = cvtpk(acc[mi][ni][2], acc[mi][ni][3]);
                    *(uint2*)(vt + (((size_t)(bb * NH + hh)) * DH + d) * TT + t) = pv;
                } else {
                    u16* dst = which == 0 ? oq : ok;
                    const float sc = which == 0 ? 0.18033688f : 1.0f;  // (1/8)*log2(e)
                    const unsigned p01 = cvtpk(acc[mi][ni][0] * sc, acc[mi][ni][1] * sc);
                    const unsigned p23 = cvtpk(acc[mi][ni][2] * sc, acc[mi][ni][3] * sc);
                    u16* db = dst + (((size_t)(bb * NH + hh)) * TT + t) * DH + d;
                    db[0] = (u16)p01;
                    db[DH] = (u16)(p01 >> 16);
                    db[2 * DH] = (u16)p23;
                    db[3 * DH] = (u16)(p23 >> 16);
                }
            } else {
                const int n = n0 + ni * 16 + l15;
                const float bn_ = bias[n];
                const float g0 = gelu_fast(acc[mi][ni][0] + bn_);
                const float g1 = gelu_fast(acc[mi][ni][1] + bn_);
                const float g2 = gelu_fast(acc[mi][ni][2] + bn_);
                const float g3 = gelu_fast(acc[mi][ni][3] + bn_);
                const unsigned p01 = cvtpk(g0, g1);
                const unsigned p23 = cvtpk(g2, g3);
                u16* db = outbf + (size_t)(m0 + mi * 16 + 4 * lg) * N + n;
                db[0] = (u16)p01;
                db[N] = (u16)(p01 >> 16);
                db[2 * N] = (u16)p23;
                db[3 * N] = (u16)(p23 >> 16);
            }
        }
    }
}

// ---------------- 128x128 bf16 MFMA GEMM ----------------
// SPLIT = number of K-splits (1 = none). MODE 3 + SPLIT>1: ks>0 blocks write bf16
// partials to pb1/pb2/pb3; ks==0 writes resid+C+bias fp32.
// DBUF=0: single-buffered m97 structure (32 KB LDS -> up to 5 blocks/CU).
template <int MODE, int DBUF, int SPLIT>
__global__ __launch_bounds__(256) void gemm_kernel(
    const u16* __restrict__ A, const u16* __restrict__ Bt, int M, int N, int K,
    const float* __restrict__ resid, float* __restrict__ outf,
    const float* __restrict__ bias,
    u16* __restrict__ pb1, u16* __restrict__ pb2, u16* __restrict__ pb3) {
    __shared__ __align__(16) u16 Alds[DBUF + 1][128][64];
    __shared__ __align__(16) u16 Blds[DBUF + 1][128][64];
    const int tid = threadIdx.x;
    const int lane = tid & 63;
    const int w = tid >> 6;
    const int wr = w >> 1, wc = w & 1;
    int bid = blockIdx.x + gridDim.x * blockIdx.y;
    const int nwg = gridDim.x * gridDim.y;
    bid = (bid & 7) * (nwg >> 3) + (bid >> 3);
    int mrow = bid / gridDim.x;
    int ks = 0;
    if constexpr (SPLIT > 1) {
        const int mtiles = (nwg / gridDim.x) / SPLIT;
        ks = mrow / mtiles;
        mrow -= ks * mtiles;
    }
    const int bm = mrow * 128, bn = (bid % gridDim.x) * 128;
    const int kbeg = SPLIT > 1 ? ks * (K / SPLIT) : 0;
    const int kend = kbeg + K / SPLIT;
    const int l15 = lane & 15, lg = lane >> 4;
    const int srow = tid >> 3, pch = tid & 7;
    const int lc = pch ^ (srow & 7);

    f32x4 acc[4][4] = {};
    const u16* Ap = A + (size_t)(bm + srow) * K + lc * 8;
    const u16* Bp = Bt + (size_t)(bn + srow) * K + lc * 8;

#define STAGE(buf, k0)                                                          \
    {                                                                           \
        _Pragma("unroll") for (int i = 0; i < 4; ++i) {                         \
            gload_lds16(Ap + (size_t)(32 * i) * K + (k0), &Alds[buf][srow + 32 * i][pch * 8]); \
            gload_lds16(Bp + (size_t)(32 * i) * K + (k0), &Blds[buf][srow + 32 * i][pch * 8]); \
        }                                                                       \
    }

#define COMPUTE(buf)                                                            \
    {                                                                           \
        _Pragma("unroll") for (int kk = 0; kk < 2; ++kk) {                      \
            bf16x8 af[4], bfr[4];                                               \
            _Pragma("unroll") for (int f = 0; f < 4; ++f) {                     \
                const int ar = wr * 64 + f * 16 + l15;                          \
                const int br = wc * 64 + f * 16 + l15;                          \
                const int kch = kk * 4 + lg;                                    \
                af[f] = *(const bf16x8*)&Alds[buf][ar][(kch ^ (ar & 7)) * 8];   \
                bfr[f] = *(const bf16x8*)&Blds[buf][br][(kch ^ (br & 7)) * 8];  \
            }                                                                   \
            _Pragma("unroll") for (int mi = 0; mi < 4; ++mi)                    \
                _Pragma("unroll") for (int ni = 0; ni < 4; ++ni)                \
                    acc[mi][ni] = mfma_bf16(af[mi], bfr[ni], acc[mi][ni]);      \
        }                                                                       \
    }

    if constexpr (DBUF == 0) {
        for (int k0 = kbeg; k0 < kend; k0 += 64) {
            STAGE(0, k0);
            __syncthreads();
            COMPUTE(0);
            __syncthreads();
        }
    } else {
        STAGE(0, kbeg);
        for (int k0 = kbeg; k0 < kend; k0 += 64) {
            const int cur = ((k0 - kbeg) >> 6) & 1;
            if (k0 + 64 < kend) {
                STAGE(cur ^ 1, k0 + 64);
                asm volatile("s_waitcnt vmcnt(8)" ::: "memory");
            } else {
                asm volatile("s_waitcnt vmcnt(0)" ::: "memory");
            }
            __builtin_amdgcn_sched_barrier(0);
            __builtin_amdgcn_s_barrier();
            __builtin_amdgcn_sched_barrier(0);
            COMPUTE(cur);
            __builtin_amdgcn_s_barrier();
        }
    }
#undef STAGE
#undef COMPUTE

    const int m0 = bm + wr * 64, n0 = bn + wc * 64;
#pragma unroll
    for (int mi = 0; mi < 4; ++mi) {
#pragma unroll
        for (int ni = 0; ni < 4; ++ni) {
            const int n = n0 + ni * 16 + l15;
            if (MODE == 3 && SPLIT > 1 && ks > 0) {
                u16* pb = ks == 1 ? pb1 : (ks == 2 ? pb2 : pb3);
                const unsigned q01 = cvtpk(acc[mi][ni][0], acc[mi][ni][1]);
                const unsigned q23 = cvtpk(acc[mi][ni][2], acc[mi][ni][3]);
                u16* db = pb + (size_t)(m0 + mi * 16 + 4 * lg) * N + n;
                db[0] = (u16)q01;
                db[N] = (u16)(q01 >> 16);
                db[2 * N] = (u16)q23;
                db[3 * N] = (u16)(q23 >> 16);
            } else {
#pragma unroll
                for (int r = 0; r < 4; ++r) {
                    const int m = m0 + mi * 16 + 4 * lg + r;
                    const float v = acc[mi][ni][r];
                    const size_t o = (size_t)m * N + n;
                    if constexpr (MODE == 1) {
                        outf[o] = resid[o] + v;
                    } else {
                        outf[o] = resid[o] + v + bias[n];
                    }
                }
            }
        }
    }
}

// ---------------- flash attention, causal, swapped-operand MFMA ----------------
__global__ __launch_bounds__(256) void attn_kernel(const u16* __restrict__ Q,
                                                   const u16* __restrict__ Kg,
                                                   const u16* __restrict__ Vtg,
                                                   u16* __restrict__ O) {
    __shared__ __align__(16) u16 Klds[4][64][64];
    __shared__ __align__(16) u16 Vlds[4][64][64];
    const int tid = threadIdx.x, lane = tid & 63, w = tid >> 6;
    const int l15 = lane & 15, lg = lane >> 4;

    int id = blockIdx.x + (blockIdx.y << 4);
    int sw = (id & 7) * 64 + (id >> 3);  // XCD k -> heads 4k..4k+3
    const int p = sw & 15, bh = sw >> 4;
    const size_t base = (size_t)bh * TT * DH;
    const int b = bh >> 4, hh = bh & 15;

    const int srow = tid >> 3, pch = tid & 7;
    const int lc = pch ^ (srow & 7);

    const int src0 = (((2 * lg) & 3) << 4) | l15;
    const int src1 = src0 + 16;
    const bool hi = (lg >> 1) != 0;

#define ASTAGE(buf, kv)                                                                     \
    {                                                                                       \
        gload_lds16(Kg + base + (size_t)((kv) * 64 + srow) * DH + lc * 8,                   \
                    &Klds[buf][srow][pch * 8]);                                             \
        gload_lds16(Kg + base + (size_t)((kv) * 64 + srow + 32) * DH + lc * 8,              \
                    &Klds[buf][srow + 32][pch * 8]);                                        \
        gload_lds16(Vtg + base + (size_t)srow * TT + (kv) * 64 + lc * 8,                    \
                    &Vlds[buf][srow][pch * 8]);                                             \
        gload_lds16(Vtg + base + (size_t)(srow + 32) * TT + (kv) * 64 + lc * 8,             \
                    &Vlds[buf][srow + 32][pch * 8]);                                        \
    }

    for (int half = 0; half < 2; ++half) {
        const int qt = half ? (31 - p) : p;
        const int nkv = qt + 1;
        const int qrow = qt * 64 + w * 16 + l15;
        uint4 qu0 = *(const uint4*)(Q + base + (size_t)qrow * DH + 8 * lg);
        uint4 qu1 = *(const uint4*)(Q + base + (size_t)qrow * DH + 32 + 8 * lg);
        asm volatile("" : "+v"(qu0.x), "+v"(qu0.y), "+v"(qu0.z), "+v"(qu0.w),
                          "+v"(qu1.x), "+v"(qu1.y), "+v"(qu1.z), "+v"(qu1.w));
        const bf16x8 qf0 = *(const bf16x8*)&qu0;
        const bf16x8 qf1 = *(const bf16x8*)&qu1;

        f32x4 o[4] = {};
        float lsum = 0.0f;

        auto compute_tile = [&](int buf, bool masked, int kvi) {
            f32x4 s[4] = {};
            __builtin_amdgcn_s_setprio(1);
#pragma unroll
            for (int nf = 0; nf < 4; ++nf) {
                const int row = nf * 16 + l15;
                bf16x8 kb0 = *(const bf16x8*)&Klds[buf][row][(lg ^ (l15 & 7)) * 8];
                bf16x8 kb1 = *(const bf16x8*)&Klds[buf][row][((4 + lg) ^ (l15 & 7)) * 8];
                s[nf] = mfma_bf16(kb0, qf0, s[nf]);
                s[nf] = mfma_bf16(kb1, qf1, s[nf]);
            }
            __builtin_amdgcn_s_setprio(0);

            if (masked) {
#pragma unroll
                for (int nf = 0; nf < 4; ++nf) {
                    const int tg = kvi * 64 + nf * 16 + 4 * lg;
#pragma unroll
                    for (int r = 0; r < 4; ++r)
                        if (tg + r > qrow) s[nf][r] = -1e30f;
                }
            }

            float ps = 0.0f;
#pragma unroll
            for (int nf = 0; nf < 4; ++nf) {
#pragma unroll
                for (int r = 0; r < 4; ++r) {
                    const float pp = exp2f(s[nf][r]);
                    s[nf][r] = pp;
                    ps += pp;
                }
            }
            lsum += ps;

            unsigned pk[4][2];
#pragma unroll
            for (int nf = 0; nf < 4; ++nf) {
                pk[nf][0] = cvtpk(s[nf][0], s[nf][1]);
                pk[nf][1] = cvtpk(s[nf][2], s[nf][3]);
            }
            bf16x8 pa[2];
#pragma unroll
            for (int kf = 0; kf < 2; ++kf) {
                unsigned a0 = __shfl((int)pk[2 * kf][0], src0);
                unsigned a1 = __shfl((int)pk[2 * kf][1], src0);
                unsigned a2 = __shfl((int)pk[2 * kf][0], src1);
                unsigned a3 = __shfl((int)pk[2 * kf][1], src1);
                unsigned c0 = __shfl((int)pk[2 * kf + 1][0], src0);
                unsigned c1 = __shfl((int)pk[2 * kf + 1][1], src0);
                unsigned c2 = __shfl((int)pk[2 * kf + 1][0], src1);
                unsigned c3 = __shfl((int)pk[2 * kf + 1][1], src1);
                uint4 wv;
                wv.x = hi ? c0 : a0;
                wv.y = hi ? c1 : a1;
                wv.z = hi ? c2 : a2;
                wv.w = hi ? c3 : a3;
                pa[kf] = *(const bf16x8*)&wv;
            }

            __builtin_amdgcn_s_setprio(1);
#pragma unroll
            for (int nf = 0; nf < 4; ++nf) {
                const int row = nf * 16 + l15;
                bf16x8 vb0 = *(const bf16x8*)&Vlds[buf][row][(lg ^ (l15 & 7)) * 8];
                bf16x8 vb1 = *(const bf16x8*)&Vlds[buf][row][((4 + lg) ^ (l15 & 7)) * 8];
                o[nf] = mfma_bf16(vb0, pa[0], o[nf]);
                o[nf] = mfma_bf16(vb1, pa[1], o[nf]);
            }
            __builtin_amdgcn_s_setprio(0);
        };

        ASTAGE(0, 0);
        if (nkv > 1) ASTAGE(1, 1);

        for (int kv = 0; kv < nkv; kv += 2) {
            int nst = 0;
            if (kv + 2 < nkv) { ASTAGE((kv + 2) & 3, kv + 2); nst += 4; }
            if (kv + 3 < nkv) { ASTAGE((kv + 3) & 3, kv + 3); nst += 4; }
            if (nst == 8)
                asm volatile("s_waitcnt vmcnt(8)" ::: "memory");
            else if (nst == 4)
                asm volatile("s_waitcnt vmcnt(4)" ::: "memory");
            else
                asm volatile("s_waitcnt vmcnt(0)" ::: "memory");
            __builtin_amdgcn_sched_barrier(0);
            __builtin_amdgcn_s_barrier();
            __builtin_amdgcn_sched_barrier(0);

            compute_tile(kv & 3, kv == qt, kv);
            if (kv + 1 < nkv) compute_tile((kv + 1) & 3, kv + 1 == qt, kv + 1);

            __builtin_amdgcn_s_barrier();
        }

        lsum += __shfl_xor(lsum, 16);
        lsum += __shfl_xor(lsum, 32);
        const float linv = 1.0f / lsum;
#pragma unroll
        for (int nf = 0; nf < 4; ++nf) {
            uint2 pv;
            pv.x = cvtpk(o[nf][0] * linv, o[nf][1] * linv);
            pv.y = cvtpk(o[nf][2] * linv, o[nf][3] * linv);
            *(uint2*)(O + ((size_t)b * TT + qrow) * DM + hh * DH + nf * 16 + 4 * lg) = pv;
        }
    }
#undef ASTAGE
}

extern "C" void kernel_launch(void* const* d_in, const int* in_sizes, int n_in,
                              void* d_out, int out_size, void* d_ws, size_t ws_size,
                              hipStream_t stream) {
    const float* x = (const float*)d_in[0];
    const float* wqkv = (const float*)d_in[1];
    const float* wout = (const float*)d_in[2];
    const float* ln1g = (const float*)d_in[3];
    const float* ln1b = (const float*)d_in[4];
    const float* ln2g = (const float*)d_in[5];
    const float* ln2b = (const float*)d_in[6];
    const float* w1 = (const float*)d_in[7];
    const float* b1 = (const float*)d_in[8];
    const float* w2 = (const float*)d_in[9];
    const float* b2 = (const float*)d_in[10];
    float* out = (float*)d_out;
    char* ws = (char*)d_ws;

    u16* wqkv_t = (u16*)(ws + 0);          // [3072][1024] bf16 (dead by FF2)
    u16* wout_t = (u16*)(ws + 6291456);    // [1024][1024]      (dead by FF2)
    u16* w1_t   = (u16*)(ws + 8388608);    // [4096][1024]      (dead by FF2)
    u16* w2_t   = (u16*)(ws + 16777216);   // [1024][4096]
    u16* h_bf   = (u16*)(ws + 25165824);   // [4096][1024] (LN1/LN2; dead by FF2)
    u16* q_bf   = (u16*)(ws + 33554432);   // [B,H,T,Dh]
    u16* k_bf   = (u16*)(ws + 41943040);   // [B,H,T,Dh]
    u16* vt_bf  = (u16*)(ws + 50331648);   // [B,H,Dh,T]  (V^T)
    u16* at_bf  = (u16*)(ws + 58720256);   // [4096][1024]
    float* x1   = (float*)(ws + 67108864); // [4096][1024] fp32
    u16* ff1_bf = q_bf;                    // aliases q/k/vt/at (dead by FF1): [4096][4096]
    // FF2 bf16 K-quarter partials (regions dead by FF2 time):
    u16* pb1 = (u16*)(ws + 0);             // 8 MB (over wqkv_t+wout_t)
    u16* pb2 = (u16*)(ws + 8388608);       // 8 MB (over w1_t)
    u16* pb3 = (u16*)(ws + 25165824);      // 8 MB (over h_bf)

    transW<<<dim3(96, 32), 256, 0, stream>>>(wqkv, wqkv_t, 1024, 3072);
    transW<<<dim3(32, 32), 256, 0, stream>>>(wout, wout_t, 1024, 1024);
    transW<<<dim3(128, 32), 256, 0, stream>>>(w1, w1_t, 1024, 4096);
    transW<<<dim3(32, 128), 256, 0, stream>>>(w2, w2_t, 4096, 1024);

    ln_kernel<<<4096, 256, 0, stream>>>(x, ln1g, ln1b, h_bf);

    gemm256<0><<<dim3(12, 16), 512, 0, stream>>>(h_bf, wqkv_t, 4096, 3072, 1024,
                                                 q_bf, k_bf, vt_bf, nullptr, nullptr);

    attn_kernel<<<dim3(16, 32), 256, 0, stream>>>(q_bf, k_bf, vt_bf, at_bf);

    gemm_kernel<1, 1, 1><<<dim3(8, 32), 256, 0, stream>>>(at_bf, wout_t, 4096, 1024, 1024,
                                                          x, x1, nullptr,
                                                          nullptr, nullptr, nullptr);

    ln_kernel<<<4096, 256, 0, stream>>>(x1, ln2g, ln2b, h_bf);

    gemm256<2><<<dim3(16, 16), 512, 0, stream>>>(h_bf, w1_t, 4096, 4096, 1024,
                                                 nullptr, nullptr, nullptr, b1, ff1_bf);

    // FF2: split-K 4, single-buffered m97 structure, 1024 blocks (~4 blocks/CU)
    gemm_kernel<3, 0, 4><<<dim3(8, 128), 256, 0, stream>>>(ff1_bf, w2_t, 4096, 1024, 4096,
                                                           x1, out, b2,
                                                           pb1, pb2, pb3);

    add3_kernel<<<2048, 256, 0, stream>>>(out, pb1, pb2, pb3, 4096 * 1024 / 4);
}

// Round 10
// 239.875 us; speedup vs baseline: 1.0298x; 1.0298x over previous
//
#include <hip/hip_runtime.h>
#include <hip/hip_bf16.h>
#include <cstdint>

#define DM 1024
#define DFF 4096
#define NB 2
#define TT 2048
#define NH 16
#define DH 64

typedef unsigned short u16;
typedef __bf16 bf16x8 __attribute__((ext_vector_type(8)));
typedef float f32x4 __attribute__((ext_vector_type(4)));

__device__ __forceinline__ u16 f2b(float f) {
    union { float f; unsigned u; } v; v.f = f;
    unsigned u = v.u;
    return (u16)((u + 0x7FFFu + ((u >> 16) & 1u)) >> 16);
}

__device__ __forceinline__ float b2f(u16 u) {
    union { unsigned x; float f; } v;
    v.x = ((unsigned)u) << 16;
    return v.f;
}

__device__ __forceinline__ unsigned cvtpk(float a, float b) {
    unsigned r;
    asm("v_cvt_pk_bf16_f32 %0, %1, %2" : "=v"(r) : "v"(a), "v"(b));
    return r;
}

// gelu(z) = z * sigmoid(2*0.79788456*(z+0.044715 z^3)); exp2-based, ~7 VALU ops.
__device__ __forceinline__ float gelu_fast(float z) {
    const float u = z * z;
    const float w = z * __builtin_fmaf(u, 0.10294324f, 2.3022082f);
    const float e = exp2f(w);
    const float r = __builtin_amdgcn_rcpf(1.0f + e);
    return z - z * r;
}

__device__ __forceinline__ f32x4 mfma_bf16(bf16x8 a, bf16x8 b, f32x4 c) {
    return __builtin_amdgcn_mfma_f32_16x16x32_bf16(a, b, c, 0, 0, 0);
}

__device__ __forceinline__ void gload_lds16(const void* g, void* l) {
    __builtin_amdgcn_global_load_lds((const __attribute__((address_space(1))) unsigned int*)g,
                                     (__attribute__((address_space(3))) unsigned int*)l, 16, 0, 0);
}

// ---------------- transpose + fp32->bf16 convert: Wt[n][k] = bf16(W[k][n]) ----------------
__global__ __launch_bounds__(256) void transW(const float* __restrict__ W, u16* __restrict__ Wt,
                                              int K, int N) {
    __shared__ float t[32][33];
    int tx = threadIdx.x & 31, ty = threadIdx.x >> 5;
    int k0 = blockIdx.y * 32, n0 = blockIdx.x * 32;
#pragma unroll
    for (int j = 0; j < 4; ++j)
        t[ty + 8 * j][tx] = W[(size_t)(k0 + ty + 8 * j) * N + n0 + tx];
    __syncthreads();
#pragma unroll
    for (int j = 0; j < 4; ++j)
        Wt[(size_t)(n0 + ty + 8 * j) * K + k0 + tx] = f2b(t[tx][ty + 8 * j]);
}

// ---------------- LayerNorm fp32 -> bf16 ----------------
__global__ __launch_bounds__(256) void ln_kernel(const float* __restrict__ X,
                                                 const float* __restrict__ g,
                                                 const float* __restrict__ bt,
                                                 u16* __restrict__ H) {
    int row = blockIdx.x, tid = threadIdx.x;
    float4 v = ((const float4*)(X + (size_t)row * DM))[tid];
    float s = v.x + v.y + v.z + v.w;
    float ss = v.x * v.x + v.y * v.y + v.z * v.z + v.w * v.w;
#pragma unroll
    for (int off = 32; off >= 1; off >>= 1) {
        s += __shfl_xor(s, off);
        ss += __shfl_xor(ss, off);
    }
    __shared__ float sb[8];
    int w = tid >> 6, lane = tid & 63;
    if (lane == 0) { sb[w] = s; sb[4 + w] = ss; }
    __syncthreads();
    s = sb[0] + sb[1] + sb[2] + sb[3];
    ss = sb[4] + sb[5] + sb[6] + sb[7];
    float mu = s * (1.0f / DM);
    float var = ss * (1.0f / DM) - mu * mu;
    float rstd = rsqrtf(var + 1e-5f);
    float4 gv = ((const float4*)g)[tid];
    float4 bv = ((const float4*)bt)[tid];
    uint2 hv;
    hv.x = cvtpk((v.x - mu) * rstd * gv.x + bv.x, (v.y - mu) * rstd * gv.y + bv.y);
    hv.y = cvtpk((v.z - mu) * rstd * gv.z + bv.z, (v.w - mu) * rstd * gv.w + bv.w);
    ((uint2*)(H + (size_t)row * DM))[tid] = hv;
}

// ---------------- out += p1 + p2 + p3 (bf16 partials) ----------------
__global__ __launch_bounds__(256) void add3_kernel(float* __restrict__ out,
                                                   const u16* __restrict__ p1,
                                                   const u16* __restrict__ p2,
                                                   const u16* __restrict__ p3, int n4) {
    int idx = blockIdx.x * 256 + threadIdx.x;
    const int stride = gridDim.x * 256;
    for (; idx < n4; idx += stride) {
        float4 a = ((const float4*)out)[idx];
        ushort4 b1 = ((const ushort4*)p1)[idx];
        ushort4 b2 = ((const ushort4*)p2)[idx];
        ushort4 b3 = ((const ushort4*)p3)[idx];
        a.x += b2f(b1.x) + b2f(b2.x) + b2f(b3.x);
        a.y += b2f(b1.y) + b2f(b2.y) + b2f(b3.y);
        a.z += b2f(b1.z) + b2f(b2.z) + b2f(b3.z);
        a.w += b2f(b1.w) + b2f(b2.w) + b2f(b3.w);
        ((float4*)out)[idx] = a;
    }
}

// ================= 256x256 8-phase GEMM (T2+T3+T4+T5) =================
// 512 threads = 8 waves (2M x 4N); BK=64; per-wave C = 128x64 (8x4 16x16 frags).
// SPLIT>1: grid y = (M/256)*SPLIT; ks>0 writes bf16 partials (MODE 3).
// MODE 0: qkv scatter; MODE 2: gelu(C+bias) bf16; MODE 3: resid+C+bias fp32 / partials.
template <int MODE, int SPLIT>
__global__ __launch_bounds__(512, 2) void gemm256(
    const u16* __restrict__ A, const u16* __restrict__ Bt, int M, int N, int K,
    u16* __restrict__ oq, u16* __restrict__ ok, u16* __restrict__ vt,
    const float* __restrict__ bias, u16* __restrict__ outbf,
    const float* __restrict__ resid, float* __restrict__ outf,
    u16* __restrict__ pb1, u16* __restrict__ pb2, u16* __restrict__ pb3) {
    __shared__ __align__(16) u16 Alds[2][256][64];
    __shared__ __align__(16) u16 Blds[2][256][64];
    const int tid = threadIdx.x;
    const int lane = tid & 63, w = tid >> 6;
    const int wm = w >> 2, wn = w & 3;
    const int l15 = lane & 15, lg = lane >> 4;
    int bid = blockIdx.x + gridDim.x * blockIdx.y;
    const int nwg = gridDim.x * gridDim.y;
    bid = (bid & 7) * (nwg >> 3) + (bid >> 3);
    int mrow = bid / gridDim.x;
    int ks = 0;
    if constexpr (SPLIT > 1) {
        const int mtiles = (nwg / gridDim.x) / SPLIT;
        ks = mrow / mtiles;
        mrow -= ks * mtiles;
    }
    const int bm = mrow * 256, bn = (bid % gridDim.x) * 256;
    const int kbeg = SPLIT > 1 ? ks * (K / SPLIT) : 0;
    const int srow = tid >> 3, pch = tid & 7;
    const int lc = pch ^ (srow & 7);

    const u16* Ap = A + (size_t)(bm + srow) * K + kbeg + lc * 8;
    const u16* Bp = Bt + (size_t)(bn + srow) * K + kbeg + lc * 8;

    f32x4 acc[8][4] = {};
    bf16x8 bf[4][2];
    const int NT = (K / SPLIT) >> 6;  // even, >= 2

#define SA256(buf, t)                                                           \
    {                                                                           \
        _Pragma("unroll") for (int j = 0; j < 4; ++j)                           \
            gload_lds16(Ap + (size_t)(64 * j) * K + (t) * 64,                   \
                        &Alds[buf][srow + 64 * j][pch * 8]);                    \
    }
#define SB256(buf, t)                                                           \
    {                                                                           \
        _Pragma("unroll") for (int j = 0; j < 4; ++j)                           \
            gload_lds16(Bp + (size_t)(64 * j) * K + (t) * 64,                   \
                        &Blds[buf][srow + 64 * j][pch * 8]);                    \
    }

#define PHASE(BUF, P, STAGE, WAIT)                                              \
    {                                                                           \
        bf16x8 af[2][2];                                                        \
        _Pragma("unroll") for (int i = 0; i < 2; ++i) {                         \
            const int row = wm * 128 + (2 * (P) + i) * 16 + l15;                \
            _Pragma("unroll") for (int ks_ = 0; ks_ < 2; ++ks_)                 \
                af[i][ks_] =                                                    \
                    *(const bf16x8*)&Alds[BUF][row][((ks_ * 4 + lg) ^ (row & 7)) * 8]; \
        }                                                                       \
        if constexpr ((P) == 0) {                                               \
            _Pragma("unroll") for (int nf = 0; nf < 4; ++nf) {                  \
                const int row = wn * 64 + nf * 16 + l15;                        \
                _Pragma("unroll") for (int ks_ = 0; ks_ < 2; ++ks_)             \
                    bf[nf][ks_] =                                               \
                        *(const bf16x8*)&Blds[BUF][row][((ks_ * 4 + lg) ^ (row & 7)) * 8]; \
            }                                                                   \
        }                                                                       \
        STAGE;                                                                  \
        WAIT;                                                                   \
        __builtin_amdgcn_s_barrier();                                           \
        asm volatile("s_waitcnt lgkmcnt(0)" ::: "memory");                      \
        __builtin_amdgcn_sched_barrier(0);                                      \
        __builtin_amdgcn_s_setprio(1);                                          \
        _Pragma("unroll") for (int i = 0; i < 2; ++i)                           \
            _Pragma("unroll") for (int nf = 0; nf < 4; ++nf)                    \
                _Pragma("unroll") for (int ks_ = 0; ks_ < 2; ++ks_)             \
                    acc[2 * (P) + i][nf] =                                      \
                        mfma_bf16(af[i][ks_], bf[nf][ks_], acc[2 * (P) + i][nf]); \
        __builtin_amdgcn_s_setprio(0);                                          \
        __builtin_amdgcn_s_barrier();                                           \
    }

    SB256(0, 0);
    SA256(0, 0);
    SB256(1, 1);
    asm volatile("s_waitcnt vmcnt(4)" ::: "memory");
    __builtin_amdgcn_sched_barrier(0);
    __builtin_amdgcn_s_barrier();

    for (int it = 0; it < (NT >> 1); ++it) {
        const int t0 = 2 * it;
        const bool more = (t0 + 2 < NT);
        PHASE(0, 0, { SA256(1, t0 + 1); }, {});
        PHASE(0, 1, { if (more) SB256(0, t0 + 2); }, {});
        PHASE(0, 2, {}, {});
        PHASE(0, 3, {}, {
            if (more) { asm volatile("s_waitcnt vmcnt(4)" ::: "memory"); }
            else { asm volatile("s_waitcnt vmcnt(0)" ::: "memory"); }
            __builtin_amdgcn_sched_barrier(0);
        });
        PHASE(1, 0, { if (more) SA256(0, t0 + 2); }, {});
        PHASE(1, 1, { if (more) SB256(1, t0 + 3); }, {});
        PHASE(1, 2, {}, {});
        PHASE(1, 3, {}, {
            if (more) {
                asm volatile("s_waitcnt vmcnt(4)" ::: "memory");
                __builtin_amdgcn_sched_barrier(0);
            }
        });
    }
#undef PHASE
#undef SA256
#undef SB256

    const int m0 = bm + wm * 128, n0 = bn + wn * 64;
#pragma unroll
    for (int mi = 0; mi < 8; ++mi) {
#pragma unroll
        for (int ni = 0; ni < 4; ++ni) {
            if constexpr (MODE == 0) {
                const int n = n0 + ni * 16 + l15;
                const int which = n >> 10;
                const int hh = (n >> 6) & 15, d = n & 63;
                const int mbase = m0 + mi * 16 + 4 * lg;
                const int bb = mbase >> 11, t = mbase & 2047;
                if (which == 2) {
                    uint2 pv;
                    pv.x = cvtpk(acc[mi][ni][0], acc[mi][ni][1]);
                    pv.y = cvtpk(acc[mi][ni][2], acc[mi][ni][3]);
                    *(uint2*)(vt + (((size_t)(bb * NH + hh)) * DH + d) * TT + t) = pv;
                } else {
                    u16* dst = which == 0 ? oq : ok;
                    const float sc = which == 0 ? 0.18033688f : 1.0f;  // (1/8)*log2(e)
                    const unsigned p01 = cvtpk(acc[mi][ni][0] * sc, acc[mi][ni][1] * sc);
                    const unsigned p23 = cvtpk(acc[mi][ni][2] * sc, acc[mi][ni][3] * sc);
                    u16* db = dst + (((size_t)(bb * NH + hh)) * TT + t) * DH + d;
                    db[0] = (u16)p01;
                    db[DH] = (u16)(p01 >> 16);
                    db[2 * DH] = (u16)p23;
                    db[3 * DH] = (u16)(p23 >> 16);
                }
            } else if constexpr (MODE == 2) {
                const int n = n0 + ni * 16 + l15;
                const float bn_ = bias[n];
                const float g0 = gelu_fast(acc[mi][ni][0] + bn_);
                const float g1 = gelu_fast(acc[mi][ni][1] + bn_);
                const float g2 = gelu_fast(acc[mi][ni][2] + bn_);
                const float g3 = gelu_fast(acc[mi][ni][3] + bn_);
                const unsigned p01 = cvtpk(g0, g1);
                const unsigned p23 = cvtpk(g2, g3);
                u16* db = outbf + (size_t)(m0 + mi * 16 + 4 * lg) * N + n;
                db[0] = (u16)p01;
                db[N] = (u16)(p01 >> 16);
                db[2 * N] = (u16)p23;
                db[3 * N] = (u16)(p23 >> 16);
            } else {  // MODE 3
                const int n = n0 + ni * 16 + l15;
                if (SPLIT > 1 && ks > 0) {
                    u16* pb = ks == 1 ? pb1 : (ks == 2 ? pb2 : pb3);
                    const unsigned q01 = cvtpk(acc[mi][ni][0], acc[mi][ni][1]);
                    const unsigned q23 = cvtpk(acc[mi][ni][2], acc[mi][ni][3]);
                    u16* db = pb + (size_t)(m0 + mi * 16 + 4 * lg) * N + n;
                    db[0] = (u16)q01;
                    db[N] = (u16)(q01 >> 16);
                    db[2 * N] = (u16)q23;
                    db[3 * N] = (u16)(q23 >> 16);
                } else {
                    const float bn_ = bias[n];
#pragma unroll
                    for (int r = 0; r < 4; ++r) {
                        const int m = m0 + mi * 16 + 4 * lg + r;
                        const size_t o = (size_t)m * N + n;
                        outf[o] = resid[o] + acc[mi][ni][r] + bn_;
                    }
                }
            }
        }
    }
}

// ---------------- 128x128 bf16 MFMA GEMM (wout) ----------------
template <int MODE>
__global__ __launch_bounds__(256) void gemm_kernel(
    const u16* __restrict__ A, const u16* __restrict__ Bt, int M, int N, int K,
    const float* __restrict__ resid, float* __restrict__ outf,
    const float* __restrict__ bias) {
    __shared__ __align__(16) u16 Alds[2][128][64];
    __shared__ __align__(16) u16 Blds[2][128][64];
    const int tid = threadIdx.x;
    const int lane = tid & 63;
    const int w = tid >> 6;
    const int wr = w >> 1, wc = w & 1;
    int bid = blockIdx.x + gridDim.x * blockIdx.y;
    const int nwg = gridDim.x * gridDim.y;
    bid = (bid & 7) * (nwg >> 3) + (bid >> 3);
    const int bm = (bid / gridDim.x) * 128, bn = (bid % gridDim.x) * 128;
    const int l15 = lane & 15, lg = lane >> 4;
    const int srow = tid >> 3, pch = tid & 7;
    const int lc = pch ^ (srow & 7);

    f32x4 acc[4][4] = {};
    const u16* Ap = A + (size_t)(bm + srow) * K + lc * 8;
    const u16* Bp = Bt + (size_t)(bn + srow) * K + lc * 8;

#define STAGE(buf, k0)                                                          \
    {                                                                           \
        _Pragma("unroll") for (int i = 0; i < 4; ++i) {                         \
            gload_lds16(Ap + (size_t)(32 * i) * K + (k0), &Alds[buf][srow + 32 * i][pch * 8]); \
            gload_lds16(Bp + (size_t)(32 * i) * K + (k0), &Blds[buf][srow + 32 * i][pch * 8]); \
        }                                                                       \
    }

#define COMPUTE(buf)                                                            \
    {                                                                           \
        _Pragma("unroll") for (int kk = 0; kk < 2; ++kk) {                      \
            bf16x8 af[4], bfr[4];                                               \
            _Pragma("unroll") for (int f = 0; f < 4; ++f) {                     \
                const int ar = wr * 64 + f * 16 + l15;                          \
                const int br = wc * 64 + f * 16 + l15;                          \
                const int kch = kk * 4 + lg;                                    \
                af[f] = *(const bf16x8*)&Alds[buf][ar][(kch ^ (ar & 7)) * 8];   \
                bfr[f] = *(const bf16x8*)&Blds[buf][br][(kch ^ (br & 7)) * 8];  \
            }                                                                   \
            _Pragma("unroll") for (int mi = 0; mi < 4; ++mi)                    \
                _Pragma("unroll") for (int ni = 0; ni < 4; ++ni)                \
                    acc[mi][ni] = mfma_bf16(af[mi], bfr[ni], acc[mi][ni]);      \
        }                                                                       \
    }

    STAGE(0, 0);
    for (int k0 = 0; k0 < K; k0 += 64) {
        const int cur = (k0 >> 6) & 1;
        if (k0 + 64 < K) {
            STAGE(cur ^ 1, k0 + 64);
            asm volatile("s_waitcnt vmcnt(8)" ::: "memory");
        } else {
            asm volatile("s_waitcnt vmcnt(0)" ::: "memory");
        }
        __builtin_amdgcn_sched_barrier(0);
        __builtin_amdgcn_s_barrier();
        __builtin_amdgcn_sched_barrier(0);
        COMPUTE(cur);
        __builtin_amdgcn_s_barrier();
    }
#undef STAGE
#undef COMPUTE

    const int m0 = bm + wr * 64, n0 = bn + wc * 64;
#pragma unroll
    for (int mi = 0; mi < 4; ++mi) {
#pragma unroll
        for (int ni = 0; ni < 4; ++ni) {
            const int n = n0 + ni * 16 + l15;
#pragma unroll
            for (int r = 0; r < 4; ++r) {
                const int m = m0 + mi * 16 + 4 * lg + r;
                const float v = acc[mi][ni][r];
                const size_t o = (size_t)m * N + n;
                if constexpr (MODE == 1) {
                    outf[o] = resid[o] + v;
                } else {
                    outf[o] = resid[o] + v + bias[n];
                }
            }
        }
    }
}

// ---------------- flash attention, causal, swapped-operand MFMA ----------------
__global__ __launch_bounds__(256) void attn_kernel(const u16* __restrict__ Q,
                                                   const u16* __restrict__ Kg,
                                                   const u16* __restrict__ Vtg,
                                                   u16* __restrict__ O) {
    __shared__ __align__(16) u16 Klds[4][64][64];
    __shared__ __align__(16) u16 Vlds[4][64][64];
    const int tid = threadIdx.x, lane = tid & 63, w = tid >> 6;
    const int l15 = lane & 15, lg = lane >> 4;

    int id = blockIdx.x + (blockIdx.y << 4);
    int sw = (id & 7) * 64 + (id >> 3);  // XCD k -> heads 4k..4k+3
    const int p = sw & 15, bh = sw >> 4;
    const size_t base = (size_t)bh * TT * DH;
    const int b = bh >> 4, hh = bh & 15;

    const int srow = tid >> 3, pch = tid & 7;
    const int lc = pch ^ (srow & 7);

    const int src0 = (((2 * lg) & 3) << 4) | l15;
    const int src1 = src0 + 16;
    const bool hi = (lg >> 1) != 0;

#define ASTAGE(buf, kv)                                                                     \
    {                                                                                       \
        gload_lds16(Kg + base + (size_t)((kv) * 64 + srow) * DH + lc * 8,                   \
                    &Klds[buf][srow][pch * 8]);                                             \
        gload_lds16(Kg + base + (size_t)((kv) * 64 + srow + 32) * DH + lc * 8,              \
                    &Klds[buf][srow + 32][pch * 8]);                                        \
        gload_lds16(Vtg + base + (size_t)srow * TT + (kv) * 64 + lc * 8,                    \
                    &Vlds[buf][srow][pch * 8]);                                             \
        gload_lds16(Vtg + base + (size_t)(srow + 32) * TT + (kv) * 64 + lc * 8,             \
                    &Vlds[buf][srow + 32][pch * 8]);                                        \
    }

    for (int half = 0; half < 2; ++half) {
        const int qt = half ? (31 - p) : p;
        const int nkv = qt + 1;
        const int qrow = qt * 64 + w * 16 + l15;
        uint4 qu0 = *(const uint4*)(Q + base + (size_t)qrow * DH + 8 * lg);
        uint4 qu1 = *(const uint4*)(Q + base + (size_t)qrow * DH + 32 + 8 * lg);
        asm volatile("" : "+v"(qu0.x), "+v"(qu0.y), "+v"(qu0.z), "+v"(qu0.w),
                          "+v"(qu1.x), "+v"(qu1.y), "+v"(qu1.z), "+v"(qu1.w));
        const bf16x8 qf0 = *(const bf16x8*)&qu0;
        const bf16x8 qf1 = *(const bf16x8*)&qu1;

        f32x4 o[4] = {};
        float lsum = 0.0f;

        auto compute_tile = [&](int buf, bool masked, int kvi) {
            f32x4 s[4] = {};
            __builtin_amdgcn_s_setprio(1);
#pragma unroll
            for (int nf = 0; nf < 4; ++nf) {
                const int row = nf * 16 + l15;
                bf16x8 kb0 = *(const bf16x8*)&Klds[buf][row][(lg ^ (l15 & 7)) * 8];
                bf16x8 kb1 = *(const bf16x8*)&Klds[buf][row][((4 + lg) ^ (l15 & 7)) * 8];
                s[nf] = mfma_bf16(kb0, qf0, s[nf]);
                s[nf] = mfma_bf16(kb1, qf1, s[nf]);
            }
            __builtin_amdgcn_s_setprio(0);

            if (masked) {
#pragma unroll
                for (int nf = 0; nf < 4; ++nf) {
                    const int tg = kvi * 64 + nf * 16 + 4 * lg;
#pragma unroll
                    for (int r = 0; r < 4; ++r)
                        if (tg + r > qrow) s[nf][r] = -1e30f;
                }
            }

            float ps = 0.0f;
#pragma unroll
            for (int nf = 0; nf < 4; ++nf) {
#pragma unroll
                for (int r = 0; r < 4; ++r) {
                    const float pp = exp2f(s[nf][r]);
                    s[nf][r] = pp;
                    ps += pp;
                }
            }
            lsum += ps;

            unsigned pk[4][2];
#pragma unroll
            for (int nf = 0; nf < 4; ++nf) {
                pk[nf][0] = cvtpk(s[nf][0], s[nf][1]);
                pk[nf][1] = cvtpk(s[nf][2], s[nf][3]);
            }
            bf16x8 pa[2];
#pragma unroll
            for (int kf = 0; kf < 2; ++kf) {
                unsigned a0 = __shfl((int)pk[2 * kf][0], src0);
                unsigned a1 = __shfl((int)pk[2 * kf][1], src0);
                unsigned a2 = __shfl((int)pk[2 * kf][0], src1);
                unsigned a3 = __shfl((int)pk[2 * kf][1], src1);
                unsigned c0 = __shfl((int)pk[2 * kf + 1][0], src0);
                unsigned c1 = __shfl((int)pk[2 * kf + 1][1], src0);
                unsigned c2 = __shfl((int)pk[2 * kf + 1][0], src1);
                unsigned c3 = __shfl((int)pk[2 * kf + 1][1], src1);
                uint4 wv;
                wv.x = hi ? c0 : a0;
                wv.y = hi ? c1 : a1;
                wv.z = hi ? c2 : a2;
                wv.w = hi ? c3 : a3;
                pa[kf] = *(const bf16x8*)&wv;
            }

            __builtin_amdgcn_s_setprio(1);
#pragma unroll
            for (int nf = 0; nf < 4; ++nf) {
                const int row = nf * 16 + l15;
                bf16x8 vb0 = *(const bf16x8*)&Vlds[buf][row][(lg ^ (l15 & 7)) * 8];
                bf16x8 vb1 = *(const bf16x8*)&Vlds[buf][row][((4 + lg) ^ (l15 & 7)) * 8];
                o[nf] = mfma_bf16(vb0, pa[0], o[nf]);
                o[nf] = mfma_bf16(vb1, pa[1], o[nf]);
            }
            __builtin_amdgcn_s_setprio(0);
        };

        ASTAGE(0, 0);
        if (nkv > 1) ASTAGE(1, 1);

        for (int kv = 0; kv < nkv; kv += 2) {
            int nst = 0;
            if (kv + 2 < nkv) { ASTAGE((kv + 2) & 3, kv + 2); nst += 4; }
            if (kv + 3 < nkv) { ASTAGE((kv + 3) & 3, kv + 3); nst += 4; }
            if (nst == 8)
                asm volatile("s_waitcnt vmcnt(8)" ::: "memory");
            else if (nst == 4)
                asm volatile("s_waitcnt vmcnt(4)" ::: "memory");
            else
                asm volatile("s_waitcnt vmcnt(0)" ::: "memory");
            __builtin_amdgcn_sched_barrier(0);
            __builtin_amdgcn_s_barrier();
            __builtin_amdgcn_sched_barrier(0);

            compute_tile(kv & 3, kv == qt, kv);
            if (kv + 1 < nkv) compute_tile((kv + 1) & 3, kv + 1 == qt, kv + 1);

            __builtin_amdgcn_s_barrier();
        }

        lsum += __shfl_xor(lsum, 16);
        lsum += __shfl_xor(lsum, 32);
        const float linv = 1.0f / lsum;
#pragma unroll
        for (int nf = 0; nf < 4; ++nf) {
            uint2 pv;
            pv.x = cvtpk(o[nf][0] * linv, o[nf][1] * linv);
            pv.y = cvtpk(o[nf][2] * linv, o[nf][3] * linv);
            *(uint2*)(O + ((size_t)b * TT + qrow) * DM + hh * DH + nf * 16 + 4 * lg) = pv;
        }
    }
#undef ASTAGE
}

extern "C" void kernel_launch(void* const* d_in, const int* in_sizes, int n_in,
                              void* d_out, int out_size, void* d_ws, size_t ws_size,
                              hipStream_t stream) {
    const float* x = (const float*)d_in[0];
    const float* wqkv = (const float*)d_in[1];
    const float* wout = (const float*)d_in[2];
    const float* ln1g = (const float*)d_in[3];
    const float* ln1b = (const float*)d_in[4];
    const float* ln2g = (const float*)d_in[5];
    const float* ln2b = (const float*)d_in[6];
    const float* w1 = (const float*)d_in[7];
    const float* b1 = (const float*)d_in[8];
    const float* w2 = (const float*)d_in[9];
    const float* b2 = (const float*)d_in[10];
    float* out = (float*)d_out;
    char* ws = (char*)d_ws;

    u16* wqkv_t = (u16*)(ws + 0);          // [3072][1024] bf16 (dead by FF2)
    u16* wout_t = (u16*)(ws + 6291456);    // [1024][1024]      (dead by FF2)
    u16* w1_t   = (u16*)(ws + 8388608);    // [4096][1024]      (dead by FF2)
    u16* w2_t   = (u16*)(ws + 16777216);   // [1024][4096]
    u16* h_bf   = (u16*)(ws + 25165824);   // [4096][1024] (LN1/LN2; dead by FF2)
    u16* q_bf   = (u16*)(ws + 33554432);   // [B,H,T,Dh]
    u16* k_bf   = (u16*)(ws + 41943040);   // [B,H,T,Dh]
    u16* vt_bf  = (u16*)(ws + 50331648);   // [B,H,Dh,T]  (V^T)
    u16* at_bf  = (u16*)(ws + 58720256);   // [4096][1024]
    float* x1   = (float*)(ws + 67108864); // [4096][1024] fp32
    u16* ff1_bf = q_bf;                    // aliases q/k/vt/at (dead by FF1): [4096][4096]
    // FF2 bf16 K-quarter partials (regions dead by FF2 time):
    u16* pb1 = (u16*)(ws + 0);             // 8 MB (over wqkv_t+wout_t)
    u16* pb2 = (u16*)(ws + 8388608);       // 8 MB (over w1_t)
    u16* pb3 = (u16*)(ws + 25165824);      // 8 MB (over h_bf)

    transW<<<dim3(96, 32), 256, 0, stream>>>(wqkv, wqkv_t, 1024, 3072);
    transW<<<dim3(32, 32), 256, 0, stream>>>(wout, wout_t, 1024, 1024);
    transW<<<dim3(128, 32), 256, 0, stream>>>(w1, w1_t, 1024, 4096);
    transW<<<dim3(32, 128), 256, 0, stream>>>(w2, w2_t, 4096, 1024);

    ln_kernel<<<4096, 256, 0, stream>>>(x, ln1g, ln1b, h_bf);

    gemm256<0, 1><<<dim3(12, 16), 512, 0, stream>>>(h_bf, wqkv_t, 4096, 3072, 1024,
                                                    q_bf, k_bf, vt_bf, nullptr, nullptr,
                                                    nullptr, nullptr,
                                                    nullptr, nullptr, nullptr);

    attn_kernel<<<dim3(16, 32), 256, 0, stream>>>(q_bf, k_bf, vt_bf, at_bf);

    gemm_kernel<1><<<dim3(8, 32), 256, 0, stream>>>(at_bf, wout_t, 4096, 1024, 1024,
                                                    x, x1, nullptr);

    ln_kernel<<<4096, 256, 0, stream>>>(x1, ln2g, ln2b, h_bf);

    gemm256<2, 1><<<dim3(16, 16), 512, 0, stream>>>(h_bf, w1_t, 4096, 4096, 1024,
                                                    nullptr, nullptr, nullptr, b1, ff1_bf,
                                                    nullptr, nullptr,
                                                    nullptr, nullptr, nullptr);

    // FF2: 256^2 8-phase, split-K 4 -> 256 blocks (1/CU), per-block K=1024 (NT=16)
    gemm256<3, 4><<<dim3(4, 64), 512, 0, stream>>>(ff1_bf, w2_t, 4096, 1024, 4096,
                                                   nullptr, nullptr, nullptr, b2, nullptr,
                                                   x1, out,
                                                   pb1, pb2, pb3);

    add3_kernel<<<2048, 256, 0, stream>>>(out, pb1, pb2, pb3, 4096 * 1024 / 4);
}

// Round 11
// 238.694 us; speedup vs baseline: 1.0349x; 1.0049x over previous
//
#include <hip/hip_runtime.h>
#include <hip/hip_bf16.h>
#include <cstdint>

#define DM 1024
#define DFF 4096
#define NB 2
#define TT 2048
#define NH 16
#define DH 64

typedef unsigned short u16;
typedef __bf16 bf16x8 __attribute__((ext_vector_type(8)));
typedef float f32x4 __attribute__((ext_vector_type(4)));

__device__ __forceinline__ u16 f2b(float f) {
    union { float f; unsigned u; } v; v.f = f;
    unsigned u = v.u;
    return (u16)((u + 0x7FFFu + ((u >> 16) & 1u)) >> 16);
}

__device__ __forceinline__ float b2f(u16 u) {
    union { unsigned x; float f; } v;
    v.x = ((unsigned)u) << 16;
    return v.f;
}

__device__ __forceinline__ unsigned cvtpk(float a, float b) {
    unsigned r;
    asm("v_cvt_pk_bf16_f32 %0, %1, %2" : "=v"(r) : "v"(a), "v"(b));
    return r;
}

// gelu(z) = z * sigmoid(2*0.79788456*(z+0.044715 z^3)); exp2-based, ~7 VALU ops.
__device__ __forceinline__ float gelu_fast(float z) {
    const float u = z * z;
    const float w = z * __builtin_fmaf(u, 0.10294324f, 2.3022082f);
    const float e = exp2f(w);
    const float r = __builtin_amdgcn_rcpf(1.0f + e);
    return z - z * r;
}

__device__ __forceinline__ f32x4 mfma_bf16(bf16x8 a, bf16x8 b, f32x4 c) {
    return __builtin_amdgcn_mfma_f32_16x16x32_bf16(a, b, c, 0, 0, 0);
}

__device__ __forceinline__ void gload_lds16(const void* g, void* l) {
    __builtin_amdgcn_global_load_lds((const __attribute__((address_space(1))) unsigned int*)g,
                                     (__attribute__((address_space(3))) unsigned int*)l, 16, 0, 0);
}

// ---------------- transpose + fp32->bf16 convert: Wt[n][k] = bf16(W[k][n]) ----------------
__global__ __launch_bounds__(256) void transW(const float* __restrict__ W, u16* __restrict__ Wt,
                                              int K, int N) {
    __shared__ float t[32][33];
    int tx = threadIdx.x & 31, ty = threadIdx.x >> 5;
    int k0 = blockIdx.y * 32, n0 = blockIdx.x * 32;
#pragma unroll
    for (int j = 0; j < 4; ++j)
        t[ty + 8 * j][tx] = W[(size_t)(k0 + ty + 8 * j) * N + n0 + tx];
    __syncthreads();
#pragma unroll
    for (int j = 0; j < 4; ++j)
        Wt[(size_t)(n0 + ty + 8 * j) * K + k0 + tx] = f2b(t[tx][ty + 8 * j]);
}

// ---------------- LayerNorm fp32 -> bf16 ----------------
__global__ __launch_bounds__(256) void ln_kernel(const float* __restrict__ X,
                                                 const float* __restrict__ g,
                                                 const float* __restrict__ bt,
                                                 u16* __restrict__ H) {
    int row = blockIdx.x, tid = threadIdx.x;
    float4 v = ((const float4*)(X + (size_t)row * DM))[tid];
    float s = v.x + v.y + v.z + v.w;
    float ss = v.x * v.x + v.y * v.y + v.z * v.z + v.w * v.w;
#pragma unroll
    for (int off = 32; off >= 1; off >>= 1) {
        s += __shfl_xor(s, off);
        ss += __shfl_xor(ss, off);
    }
    __shared__ float sb[8];
    int w = tid >> 6, lane = tid & 63;
    if (lane == 0) { sb[w] = s; sb[4 + w] = ss; }
    __syncthreads();
    s = sb[0] + sb[1] + sb[2] + sb[3];
    ss = sb[4] + sb[5] + sb[6] + sb[7];
    float mu = s * (1.0f / DM);
    float var = ss * (1.0f / DM) - mu * mu;
    float rstd = rsqrtf(var + 1e-5f);
    float4 gv = ((const float4*)g)[tid];
    float4 bv = ((const float4*)bt)[tid];
    uint2 hv;
    hv.x = cvtpk((v.x - mu) * rstd * gv.x + bv.x, (v.y - mu) * rstd * gv.y + bv.y);
    hv.y = cvtpk((v.z - mu) * rstd * gv.z + bv.z, (v.w - mu) * rstd * gv.w + bv.w);
    ((uint2*)(H + (size_t)row * DM))[tid] = hv;
}

// ---------------- out += p1 + p2 + p3 (bf16 partials) ----------------
__global__ __launch_bounds__(256) void add3_kernel(float* __restrict__ out,
                                                   const u16* __restrict__ p1,
                                                   const u16* __restrict__ p2,
                                                   const u16* __restrict__ p3, int n4) {
    int idx = blockIdx.x * 256 + threadIdx.x;
    const int stride = gridDim.x * 256;
    for (; idx < n4; idx += stride) {
        float4 a = ((const float4*)out)[idx];
        ushort4 b1 = ((const ushort4*)p1)[idx];
        ushort4 b2 = ((const ushort4*)p2)[idx];
        ushort4 b3 = ((const ushort4*)p3)[idx];
        a.x += b2f(b1.x) + b2f(b2.x) + b2f(b3.x);
        a.y += b2f(b1.y) + b2f(b2.y) + b2f(b3.y);
        a.z += b2f(b1.z) + b2f(b2.z) + b2f(b3.z);
        a.w += b2f(b1.w) + b2f(b2.w) + b2f(b3.w);
        ((float4*)out)[idx] = a;
    }
}

// ================= 256x256 8-phase GEMM (T2+T3+T4+T5) =================
// 512 threads = 8 waves (2M x 4N); BK=64; per-wave C = 128x64 (8x4 16x16 frags).
// SPLIT>1: grid y = (M/256)*SPLIT; ks>0 writes bf16 partials (MODE 3).
// MODE 0: qkv scatter; MODE 2: gelu(C+bias) bf16; MODE 3: resid+C+bias fp32 / partials.
template <int MODE, int SPLIT>
__global__ __launch_bounds__(512, 2) void gemm256(
    const u16* __restrict__ A, const u16* __restrict__ Bt, int M, int N, int K,
    u16* __restrict__ oq, u16* __restrict__ ok, u16* __restrict__ vt,
    const float* __restrict__ bias, u16* __restrict__ outbf,
    const float* __restrict__ resid, float* __restrict__ outf,
    u16* __restrict__ pb1, u16* __restrict__ pb2, u16* __restrict__ pb3) {
    __shared__ __align__(16) u16 Alds[2][256][64];
    __shared__ __align__(16) u16 Blds[2][256][64];
    const int tid = threadIdx.x;
    const int lane = tid & 63, w = tid >> 6;
    const int wm = w >> 2, wn = w & 3;
    const int l15 = lane & 15, lg = lane >> 4;
    int bid = blockIdx.x + gridDim.x * blockIdx.y;
    const int nwg = gridDim.x * gridDim.y;
    bid = (bid & 7) * (nwg >> 3) + (bid >> 3);
    int mrow = bid / gridDim.x;
    int ks = 0;
    if constexpr (SPLIT > 1) {
        const int mtiles = (nwg / gridDim.x) / SPLIT;
        ks = mrow / mtiles;
        mrow -= ks * mtiles;
    }
    const int bm = mrow * 256, bn = (bid % gridDim.x) * 256;
    const int kbeg = SPLIT > 1 ? ks * (K / SPLIT) : 0;
    const int srow = tid >> 3, pch = tid & 7;
    const int lc = pch ^ (srow & 7);

    const u16* Ap = A + (size_t)(bm + srow) * K + kbeg + lc * 8;
    const u16* Bp = Bt + (size_t)(bn + srow) * K + kbeg + lc * 8;

    f32x4 acc[8][4] = {};
    bf16x8 bf[4][2];
    const int NT = (K / SPLIT) >> 6;  // even, >= 2

#define SA256(buf, t)                                                           \
    {                                                                           \
        _Pragma("unroll") for (int j = 0; j < 4; ++j)                           \
            gload_lds16(Ap + (size_t)(64 * j) * K + (t) * 64,                   \
                        &Alds[buf][srow + 64 * j][pch * 8]);                    \
    }
#define SB256(buf, t)                                                           \
    {                                                                           \
        _Pragma("unroll") for (int j = 0; j < 4; ++j)                           \
            gload_lds16(Bp + (size_t)(64 * j) * K + (t) * 64,                   \
                        &Blds[buf][srow + 64 * j][pch * 8]);                    \
    }

#define PHASE(BUF, P, STAGE, WAIT)                                              \
    {                                                                           \
        bf16x8 af[2][2];                                                        \
        _Pragma("unroll") for (int i = 0; i < 2; ++i) {                         \
            const int row = wm * 128 + (2 * (P) + i) * 16 + l15;                \
            _Pragma("unroll") for (int ks_ = 0; ks_ < 2; ++ks_)                 \
                af[i][ks_] =                                                    \
                    *(const bf16x8*)&Alds[BUF][row][((ks_ * 4 + lg) ^ (row & 7)) * 8]; \
        }                                                                       \
        if constexpr ((P) == 0) {                                               \
            _Pragma("unroll") for (int nf = 0; nf < 4; ++nf) {                  \
                const int row = wn * 64 + nf * 16 + l15;                        \
                _Pragma("unroll") for (int ks_ = 0; ks_ < 2; ++ks_)             \
                    bf[nf][ks_] =                                               \
                        *(const bf16x8*)&Blds[BUF][row][((ks_ * 4 + lg) ^ (row & 7)) * 8]; \
            }                                                                   \
        }                                                                       \
        STAGE;                                                                  \
        WAIT;                                                                   \
        __builtin_amdgcn_s_barrier();                                           \
        asm volatile("s_waitcnt lgkmcnt(0)" ::: "memory");                      \
        __builtin_amdgcn_sched_barrier(0);                                      \
        __builtin_amdgcn_s_setprio(1);                                          \
        _Pragma("unroll") for (int i = 0; i < 2; ++i)                           \
            _Pragma("unroll") for (int nf = 0; nf < 4; ++nf)                    \
                _Pragma("unroll") for (int ks_ = 0; ks_ < 2; ++ks_)             \
                    acc[2 * (P) + i][nf] =                                      \
                        mfma_bf16(af[i][ks_], bf[nf][ks_], acc[2 * (P) + i][nf]); \
        __builtin_amdgcn_s_setprio(0);                                          \
        __builtin_amdgcn_s_barrier();                                           \
    }

    SB256(0, 0);
    SA256(0, 0);
    SB256(1, 1);
    asm volatile("s_waitcnt vmcnt(4)" ::: "memory");
    __builtin_amdgcn_sched_barrier(0);
    __builtin_amdgcn_s_barrier();

    for (int it = 0; it < (NT >> 1); ++it) {
        const int t0 = 2 * it;
        const bool more = (t0 + 2 < NT);
        PHASE(0, 0, { SA256(1, t0 + 1); }, {});
        PHASE(0, 1, { if (more) SB256(0, t0 + 2); }, {});
        PHASE(0, 2, {}, {});
        PHASE(0, 3, {}, {
            if (more) { asm volatile("s_waitcnt vmcnt(4)" ::: "memory"); }
            else { asm volatile("s_waitcnt vmcnt(0)" ::: "memory"); }
            __builtin_amdgcn_sched_barrier(0);
        });
        PHASE(1, 0, { if (more) SA256(0, t0 + 2); }, {});
        PHASE(1, 1, { if (more) SB256(1, t0 + 3); }, {});
        PHASE(1, 2, {}, {});
        PHASE(1, 3, {}, {
            if (more) {
                asm volatile("s_waitcnt vmcnt(4)" ::: "memory");
                __builtin_amdgcn_sched_barrier(0);
            }
        });
    }
#undef PHASE
#undef SA256
#undef SB256

    const int m0 = bm + wm * 128, n0 = bn + wn * 64;
#pragma unroll
    for (int mi = 0; mi < 8; ++mi) {
#pragma unroll
        for (int ni = 0; ni < 4; ++ni) {
            if constexpr (MODE == 0) {
                const int n = n0 + ni * 16 + l15;
                const int which = n >> 10;
                const int hh = (n >> 6) & 15, d = n & 63;
                const int mbase = m0 + mi * 16 + 4 * lg;
                const int bb = mbase >> 11, t = mbase & 2047;
                if (which == 2) {
                    uint2 pv;
                    pv.x = cvtpk(acc[mi][ni][0], acc[mi][ni][1]);
                    pv.y = cvtpk(acc[mi][ni][2], acc[mi][ni][3]);
                    *(uint2*)(vt + (((size_t)(bb * NH + hh)) * DH + d) * TT + t) = pv;
                } else {
                    u16* dst = which == 0 ? oq : ok;
                    const float sc = which == 0 ? 0.18033688f : 1.0f;  // (1/8)*log2(e)
                    const unsigned p01 = cvtpk(acc[mi][ni][0] * sc, acc[mi][ni][1] * sc);
                    const unsigned p23 = cvtpk(acc[mi][ni][2] * sc, acc[mi][ni][3] * sc);
                    u16* db = dst + (((size_t)(bb * NH + hh)) * TT + t) * DH + d;
                    db[0] = (u16)p01;
                    db[DH] = (u16)(p01 >> 16);
                    db[2 * DH] = (u16)p23;
                    db[3 * DH] = (u16)(p23 >> 16);
                }
            } else if constexpr (MODE == 2) {
                const int n = n0 + ni * 16 + l15;
                const float bn_ = bias[n];
                const float g0 = gelu_fast(acc[mi][ni][0] + bn_);
                const float g1 = gelu_fast(acc[mi][ni][1] + bn_);
                const float g2 = gelu_fast(acc[mi][ni][2] + bn_);
                const float g3 = gelu_fast(acc[mi][ni][3] + bn_);
                const unsigned p01 = cvtpk(g0, g1);
                const unsigned p23 = cvtpk(g2, g3);
                u16* db = outbf + (size_t)(m0 + mi * 16 + 4 * lg) * N + n;
                db[0] = (u16)p01;
                db[N] = (u16)(p01 >> 16);
                db[2 * N] = (u16)p23;
                db[3 * N] = (u16)(p23 >> 16);
            } else {  // MODE 3
                const int n = n0 + ni * 16 + l15;
                if (SPLIT > 1 && ks > 0) {
                    u16* pb = ks == 1 ? pb1 : (ks == 2 ? pb2 : pb3);
                    const unsigned q01 = cvtpk(acc[mi][ni][0], acc[mi][ni][1]);
                    const unsigned q23 = cvtpk(acc[mi][ni][2], acc[mi][ni][3]);
                    u16* db = pb + (size_t)(m0 + mi * 16 + 4 * lg) * N + n;
                    db[0] = (u16)q01;
                    db[N] = (u16)(q01 >> 16);
                    db[2 * N] = (u16)q23;
                    db[3 * N] = (u16)(q23 >> 16);
                } else {
                    const float bn_ = bias[n];
#pragma unroll
                    for (int r = 0; r < 4; ++r) {
                        const int m = m0 + mi * 16 + 4 * lg + r;
                        const size_t o = (size_t)m * N + n;
                        outf[o] = resid[o] + acc[mi][ni][r] + bn_;
                    }
                }
            }
        }
    }
}

// ---------------- 128x128 bf16 MFMA GEMM (wout) ----------------
template <int MODE>
__global__ __launch_bounds__(256) void gemm_kernel(
    const u16* __restrict__ A, const u16* __restrict__ Bt, int M, int N, int K,
    const float* __restrict__ resid, float* __restrict__ outf,
    const float* __restrict__ bias) {
    __shared__ __align__(16) u16 Alds[2][128][64];
    __shared__ __align__(16) u16 Blds[2][128][64];
    const int tid = threadIdx.x;
    const int lane = tid & 63;
    const int w = tid >> 6;
    const int wr = w >> 1, wc = w & 1;
    int bid = blockIdx.x + gridDim.x * blockIdx.y;
    const int nwg = gridDim.x * gridDim.y;
    bid = (bid & 7) * (nwg >> 3) + (bid >> 3);
    const int bm = (bid / gridDim.x) * 128, bn = (bid % gridDim.x) * 128;
    const int l15 = lane & 15, lg = lane >> 4;
    const int srow = tid >> 3, pch = tid & 7;
    const int lc = pch ^ (srow & 7);

    f32x4 acc[4][4] = {};
    const u16* Ap = A + (size_t)(bm + srow) * K + lc * 8;
    const u16* Bp = Bt + (size_t)(bn + srow) * K + lc * 8;

#define STAGE(buf, k0)                                                          \
    {                                                                           \
        _Pragma("unroll") for (int i = 0; i < 4; ++i) {                         \
            gload_lds16(Ap + (size_t)(32 * i) * K + (k0), &Alds[buf][srow + 32 * i][pch * 8]); \
            gload_lds16(Bp + (size_t)(32 * i) * K + (k0), &Blds[buf][srow + 32 * i][pch * 8]); \
        }                                                                       \
    }

#define COMPUTE(buf)                                                            \
    {                                                                           \
        _Pragma("unroll") for (int kk = 0; kk < 2; ++kk) {                      \
            bf16x8 af[4], bfr[4];                                               \
            _Pragma("unroll") for (int f = 0; f < 4; ++f) {                     \
                const int ar = wr * 64 + f * 16 + l15;                          \
                const int br = wc * 64 + f * 16 + l15;                          \
                const int kch = kk * 4 + lg;                                    \
                af[f] = *(const bf16x8*)&Alds[buf][ar][(kch ^ (ar & 7)) * 8];   \
                bfr[f] = *(const bf16x8*)&Blds[buf][br][(kch ^ (br & 7)) * 8];  \
            }                                                                   \
            _Pragma("unroll") for (int mi = 0; mi < 4; ++mi)                    \
                _Pragma("unroll") for (int ni = 0; ni < 4; ++ni)                \
                    acc[mi][ni] = mfma_bf16(af[mi], bfr[ni], acc[mi][ni]);      \
        }                                                                       \
    }

    STAGE(0, 0);
    for (int k0 = 0; k0 < K; k0 += 64) {
        const int cur = (k0 >> 6) & 1;
        if (k0 + 64 < K) {
            STAGE(cur ^ 1, k0 + 64);
            asm volatile("s_waitcnt vmcnt(8)" ::: "memory");
        } else {
            asm volatile("s_waitcnt vmcnt(0)" ::: "memory");
        }
        __builtin_amdgcn_sched_barrier(0);
        __builtin_amdgcn_s_barrier();
        __builtin_amdgcn_sched_barrier(0);
        COMPUTE(cur);
        __builtin_amdgcn_s_barrier();
    }
#undef STAGE
#undef COMPUTE

    const int m0 = bm + wr * 64, n0 = bn + wc * 64;
#pragma unroll
    for (int mi = 0; mi < 4; ++mi) {
#pragma unroll
        for (int ni = 0; ni < 4; ++ni) {
            const int n = n0 + ni * 16 + l15;
#pragma unroll
            for (int r = 0; r < 4; ++r) {
                const int m = m0 + mi * 16 + 4 * lg + r;
                const float v = acc[mi][ni][r];
                const size_t o = (size_t)m * N + n;
                if constexpr (MODE == 1) {
                    outf[o] = resid[o] + v;
                } else {
                    outf[o] = resid[o] + v + bias[n];
                }
            }
        }
    }
}

// ---------------- flash attention, causal, swapped-operand MFMA ----------------
// Zero-shuffle PV: k-axis of PV permuted by sigma(k)=[kf|j2|lg|j1j0] on BOTH operands;
// P B-fragments = lane-local pk concatenation (no cross-lane ops); V read as 2x8B halves.
__global__ __launch_bounds__(256) void attn_kernel(const u16* __restrict__ Q,
                                                   const u16* __restrict__ Kg,
                                                   const u16* __restrict__ Vtg,
                                                   u16* __restrict__ O) {
    __shared__ __align__(16) u16 Klds[4][64][64];
    __shared__ __align__(16) u16 Vlds[4][64][64];
    const int tid = threadIdx.x, lane = tid & 63, w = tid >> 6;
    const int l15 = lane & 15, lg = lane >> 4;

    int id = blockIdx.x + (blockIdx.y << 4);
    int sw = (id & 7) * 64 + (id >> 3);  // XCD k -> heads 4k..4k+3
    const int p = sw & 15, bh = sw >> 4;
    const size_t base = (size_t)bh * TT * DH;
    const int b = bh >> 4, hh = bh & 15;

    const int srow = tid >> 3, pch = tid & 7;
    const int lc = pch ^ (srow & 7);

    const int vhalf = (lg & 1) * 8;   // byte offset of the 4-elem half within a 16B chunk
    const int vc = lg >> 1;           // base chunk (0 or 1)

#define ASTAGE(buf, kv)                                                                     \
    {                                                                                       \
        gload_lds16(Kg + base + (size_t)((kv) * 64 + srow) * DH + lc * 8,                   \
                    &Klds[buf][srow][pch * 8]);                                             \
        gload_lds16(Kg + base + (size_t)((kv) * 64 + srow + 32) * DH + lc * 8,              \
                    &Klds[buf][srow + 32][pch * 8]);                                        \
        gload_lds16(Vtg + base + (size_t)srow * TT + (kv) * 64 + lc * 8,                    \
                    &Vlds[buf][srow][pch * 8]);                                             \
        gload_lds16(Vtg + base + (size_t)(srow + 32) * TT + (kv) * 64 + lc * 8,             \
                    &Vlds[buf][srow + 32][pch * 8]);                                        \
    }

    for (int half = 0; half < 2; ++half) {
        const int qt = half ? (31 - p) : p;
        const int nkv = qt + 1;
        const int qrow = qt * 64 + w * 16 + l15;
        uint4 qu0 = *(const uint4*)(Q + base + (size_t)qrow * DH + 8 * lg);
        uint4 qu1 = *(const uint4*)(Q + base + (size_t)qrow * DH + 32 + 8 * lg);
        asm volatile("" : "+v"(qu0.x), "+v"(qu0.y), "+v"(qu0.z), "+v"(qu0.w),
                          "+v"(qu1.x), "+v"(qu1.y), "+v"(qu1.z), "+v"(qu1.w));
        const bf16x8 qf0 = *(const bf16x8*)&qu0;
        const bf16x8 qf1 = *(const bf16x8*)&qu1;

        f32x4 o[4] = {};
        float lsum = 0.0f;

        auto compute_tile = [&](int buf, bool masked, int kvi) {
            // S^T = K Q^T
            f32x4 s[4] = {};
            __builtin_amdgcn_s_setprio(1);
#pragma unroll
            for (int nf = 0; nf < 4; ++nf) {
                const int row = nf * 16 + l15;
                bf16x8 kb0 = *(const bf16x8*)&Klds[buf][row][(lg ^ (l15 & 7)) * 8];
                bf16x8 kb1 = *(const bf16x8*)&Klds[buf][row][((4 + lg) ^ (l15 & 7)) * 8];
                s[nf] = mfma_bf16(kb0, qf0, s[nf]);
                s[nf] = mfma_bf16(kb1, qf1, s[nf]);
            }
            __builtin_amdgcn_s_setprio(0);

            if (masked) {
#pragma unroll
                for (int nf = 0; nf < 4; ++nf) {
                    const int tg = kvi * 64 + nf * 16 + 4 * lg;
#pragma unroll
                    for (int r = 0; r < 4; ++r)
                        if (tg + r > qrow) s[nf][r] = -1e30f;
                }
            }

            // fixed-reference softmax: P = exp2(S') directly
            float ps = 0.0f;
#pragma unroll
            for (int nf = 0; nf < 4; ++nf) {
#pragma unroll
                for (int r = 0; r < 4; ++r) {
                    const float pp = exp2f(s[nf][r]);
                    s[nf][r] = pp;
                    ps += pp;
                }
            }
            lsum += ps;

            // pack P rows to bf16; under sigma, pa = lane-local concatenation (no shuffles)
            unsigned pk[4][2];
#pragma unroll
            for (int nf = 0; nf < 4; ++nf) {
                pk[nf][0] = cvtpk(s[nf][0], s[nf][1]);
                pk[nf][1] = cvtpk(s[nf][2], s[nf][3]);
            }
            uint4 pu0, pu1;
            pu0.x = pk[0][0]; pu0.y = pk[0][1]; pu0.z = pk[1][0]; pu0.w = pk[1][1];
            pu1.x = pk[2][0]; pu1.y = pk[2][1]; pu1.z = pk[3][0]; pu1.w = pk[3][1];
            const bf16x8 pa0 = *(const bf16x8*)&pu0;
            const bf16x8 pa1 = *(const bf16x8*)&pu1;

            // O^T += V^T P^T  (V columns read sigma-permuted: two 8B halves per fragment)
            __builtin_amdgcn_s_setprio(1);
#pragma unroll
            for (int nf = 0; nf < 4; ++nf) {
                const int row = nf * 16 + l15;
                const int swz = row & 7;
                const char* vb = (const char*)&Vlds[buf][row][0];
                uint2 a0 = *(const uint2*)(vb + (((vc + 0) ^ swz) * 16 + vhalf));
                uint2 a1 = *(const uint2*)(vb + (((vc + 2) ^ swz) * 16 + vhalf));
                uint2 b0 = *(const uint2*)(vb + (((vc + 4) ^ swz) * 16 + vhalf));
                uint2 b1 = *(const uint2*)(vb + (((vc + 6) ^ swz) * 16 + vhalf));
                uint4 v0; v0.x = a0.x; v0.y = a0.y; v0.z = a1.x; v0.w = a1.y;
                uint4 v1; v1.x = b0.x; v1.y = b0.y; v1.z = b1.x; v1.w = b1.y;
                o[nf] = mfma_bf16(*(const bf16x8*)&v0, pa0, o[nf]);
                o[nf] = mfma_bf16(*(const bf16x8*)&v1, pa1, o[nf]);
            }
            __builtin_amdgcn_s_setprio(0);
        };

        ASTAGE(0, 0);
        if (nkv > 1) ASTAGE(1, 1);

        for (int kv = 0; kv < nkv; kv += 2) {
            int nst = 0;
            if (kv + 2 < nkv) { ASTAGE((kv + 2) & 3, kv + 2); nst += 4; }
            if (kv + 3 < nkv) { ASTAGE((kv + 3) & 3, kv + 3); nst += 4; }
            if (nst == 8)
                asm volatile("s_waitcnt vmcnt(8)" ::: "memory");
            else if (nst == 4)
                asm volatile("s_waitcnt vmcnt(4)" ::: "memory");
            else
                asm volatile("s_waitcnt vmcnt(0)" ::: "memory");
            __builtin_amdgcn_sched_barrier(0);
            __builtin_amdgcn_s_barrier();
            __builtin_amdgcn_sched_barrier(0);

            compute_tile(kv & 3, kv == qt, kv);
            if (kv + 1 < nkv) compute_tile((kv + 1) & 3, kv + 1 == qt, kv + 1);

            __builtin_amdgcn_s_barrier();
        }

        lsum += __shfl_xor(lsum, 16);
        lsum += __shfl_xor(lsum, 32);
        const float linv = 1.0f / lsum;
#pragma unroll
        for (int nf = 0; nf < 4; ++nf) {
            uint2 pv;
            pv.x = cvtpk(o[nf][0] * linv, o[nf][1] * linv);
            pv.y = cvtpk(o[nf][2] * linv, o[nf][3] * linv);
            *(uint2*)(O + ((size_t)b * TT + qrow) * DM + hh * DH + nf * 16 + 4 * lg) = pv;
        }
    }
#undef ASTAGE
}

extern "C" void kernel_launch(void* const* d_in, const int* in_sizes, int n_in,
                              void* d_out, int out_size, void* d_ws, size_t ws_size,
                              hipStream_t stream) {
    const float* x = (const float*)d_in[0];
    const float* wqkv = (const float*)d_in[1];
    const float* wout = (const float*)d_in[2];
    const float* ln1g = (const float*)d_in[3];
    const float* ln1b = (const float*)d_in[4];
    const float* ln2g = (const float*)d_in[5];
    const float* ln2b = (const float*)d_in[6];
    const float* w1 = (const float*)d_in[7];
    const float* b1 = (const float*)d_in[8];
    const float* w2 = (const float*)d_in[9];
    const float* b2 = (const float*)d_in[10];
    float* out = (float*)d_out;
    char* ws = (char*)d_ws;

    u16* wqkv_t = (u16*)(ws + 0);          // [3072][1024] bf16 (dead by FF2)
    u16* wout_t = (u16*)(ws + 6291456);    // [1024][1024]      (dead by FF2)
    u16* w1_t   = (u16*)(ws + 8388608);    // [4096][1024]      (dead by FF2)
    u16* w2_t   = (u16*)(ws + 16777216);   // [1024][4096]
    u16* h_bf   = (u16*)(ws + 25165824);   // [4096][1024] (LN1/LN2; dead by FF2)
    u16* q_bf   = (u16*)(ws + 33554432);   // [B,H,T,Dh]
    u16* k_bf   = (u16*)(ws + 41943040);   // [B,H,T,Dh]
    u16* vt_bf  = (u16*)(ws + 50331648);   // [B,H,Dh,T]  (V^T)
    u16* at_bf  = (u16*)(ws + 58720256);   // [4096][1024]
    float* x1   = (float*)(ws + 67108864); // [4096][1024] fp32
    u16* ff1_bf = q_bf;                    // aliases q/k/vt/at (dead by FF1): [4096][4096]
    // FF2 bf16 K-quarter partials (regions dead by FF2 time):
    u16* pb1 = (u16*)(ws + 0);             // 8 MB (over wqkv_t+wout_t)
    u16* pb2 = (u16*)(ws + 8388608);       // 8 MB (over w1_t)
    u16* pb3 = (u16*)(ws + 25165824);      // 8 MB (over h_bf)

    transW<<<dim3(96, 32), 256, 0, stream>>>(wqkv, wqkv_t, 1024, 3072);
    transW<<<dim3(32, 32), 256, 0, stream>>>(wout, wout_t, 1024, 1024);
    transW<<<dim3(128, 32), 256, 0, stream>>>(w1, w1_t, 1024, 4096);
    transW<<<dim3(32, 128), 256, 0, stream>>>(w2, w2_t, 4096, 1024);

    ln_kernel<<<4096, 256, 0, stream>>>(x, ln1g, ln1b, h_bf);

    gemm256<0, 1><<<dim3(12, 16), 512, 0, stream>>>(h_bf, wqkv_t, 4096, 3072, 1024,
                                                    q_bf, k_bf, vt_bf, nullptr, nullptr,
                                                    nullptr, nullptr,
                                                    nullptr, nullptr, nullptr);

    attn_kernel<<<dim3(16, 32), 256, 0, stream>>>(q_bf, k_bf, vt_bf, at_bf);

    gemm_kernel<1><<<dim3(8, 32), 256, 0, stream>>>(at_bf, wout_t, 4096, 1024, 1024,
                                                    x, x1, nullptr);

    ln_kernel<<<4096, 256, 0, stream>>>(x1, ln2g, ln2b, h_bf);

    gemm256<2, 1><<<dim3(16, 16), 512, 0, stream>>>(h_bf, w1_t, 4096, 4096, 1024,
                                                    nullptr, nullptr, nullptr, b1, ff1_bf,
                                                    nullptr, nullptr,
                                                    nullptr, nullptr, nullptr);

    // FF2: 256^2 8-phase, split-K 4 -> 256 blocks (1/CU), per-block K=1024 (NT=16)
    gemm256<3, 4><<<dim3(4, 64), 512, 0, stream>>>(ff1_bf, w2_t, 4096, 1024, 4096,
                                                   nullptr, nullptr, nullptr, b2, nullptr,
                                                   x1, out,
                                                   pb1, pb2, pb3);

    add3_kernel<<<2048, 256, 0, stream>>>(out, pb1, pb2, pb3, 4096 * 1024 / 4);
}

// Round 12
// 221.233 us; speedup vs baseline: 1.1166x; 1.0789x over previous
//
#include <hip/hip_runtime.h>
#include <hip/hip_bf16.h>
#include <cstdint>

#define DM 1024
#define DFF 4096
#define NB 2
#define TT 2048
#define NH 16
#define DH 64

typedef unsigned short u16;
typedef __bf16 bf16x8 __attribute__((ext_vector_type(8)));
typedef float f32x4 __attribute__((ext_vector_type(4)));

__device__ __forceinline__ u16 f2b(float f) {
    union { float f; unsigned u; } v; v.f = f;
    unsigned u = v.u;
    return (u16)((u + 0x7FFFu + ((u >> 16) & 1u)) >> 16);
}

__device__ __forceinline__ float b2f(u16 u) {
    union { unsigned x; float f; } v;
    v.x = ((unsigned)u) << 16;
    return v.f;
}

__device__ __forceinline__ unsigned cvtpk(float a, float b) {
    unsigned r;
    asm("v_cvt_pk_bf16_f32 %0, %1, %2" : "=v"(r) : "v"(a), "v"(b));
    return r;
}

// gelu(z) = z * sigmoid(2*0.79788456*(z+0.044715 z^3)); exp2-based, ~7 VALU ops.
__device__ __forceinline__ float gelu_fast(float z) {
    const float u = z * z;
    const float w = z * __builtin_fmaf(u, 0.10294324f, 2.3022082f);
    const float e = exp2f(w);
    const float r = __builtin_amdgcn_rcpf(1.0f + e);
    return z - z * r;
}

__device__ __forceinline__ f32x4 mfma_bf16(bf16x8 a, bf16x8 b, f32x4 c) {
    return __builtin_amdgcn_mfma_f32_16x16x32_bf16(a, b, c, 0, 0, 0);
}

__device__ __forceinline__ void gload_lds16(const void* g, void* l) {
    __builtin_amdgcn_global_load_lds((const __attribute__((address_space(1))) unsigned int*)g,
                                     (__attribute__((address_space(3))) unsigned int*)l, 16, 0, 0);
}

// ---------------- fused prep: 4x weight transpose+bf16 + LN1 ----------------
// blocks [0,3072): wqkv^T; [3072,4096): wout^T; [4096,8192): w1^T; [8192,12288): w2^T;
// [12288,16384): LN1 rows. All branches independent.
__global__ __launch_bounds__(256) void prep_kernel(
    const float* __restrict__ wqkv, const float* __restrict__ wout,
    const float* __restrict__ w1, const float* __restrict__ w2,
    u16* __restrict__ wqkv_t, u16* __restrict__ wout_t,
    u16* __restrict__ w1_t, u16* __restrict__ w2_t,
    const float* __restrict__ x, const float* __restrict__ g,
    const float* __restrict__ bt, u16* __restrict__ H) {
    __shared__ float t[32][33];
    __shared__ float sb[8];
    const int id = blockIdx.x;
    const int tid = threadIdx.x;
    if (id < 12288) {
        const float* W;
        u16* Wt;
        int K, N, bx, by;
        if (id < 3072) {
            W = wqkv; Wt = wqkv_t; K = 1024; N = 3072; bx = id % 96; by = id / 96;
        } else if (id < 4096) {
            const int t2 = id - 3072;
            W = wout; Wt = wout_t; K = 1024; N = 1024; bx = t2 % 32; by = t2 / 32;
        } else if (id < 8192) {
            const int t2 = id - 4096;
            W = w1; Wt = w1_t; K = 1024; N = 4096; bx = t2 % 128; by = t2 / 128;
        } else {
            const int t2 = id - 8192;
            W = w2; Wt = w2_t; K = 4096; N = 1024; bx = t2 % 32; by = t2 / 32;
        }
        const int tx = tid & 31, ty = tid >> 5;
        const int k0 = by * 32, n0 = bx * 32;
#pragma unroll
        for (int j = 0; j < 4; ++j)
            t[ty + 8 * j][tx] = W[(size_t)(k0 + ty + 8 * j) * N + n0 + tx];
        __syncthreads();
#pragma unroll
        for (int j = 0; j < 4; ++j)
            Wt[(size_t)(n0 + ty + 8 * j) * K + k0 + tx] = f2b(t[tx][ty + 8 * j]);
    } else {
        const int row = id - 12288;
        float4 v = ((const float4*)(x + (size_t)row * DM))[tid];
        float s = v.x + v.y + v.z + v.w;
        float ss = v.x * v.x + v.y * v.y + v.z * v.z + v.w * v.w;
#pragma unroll
        for (int off = 32; off >= 1; off >>= 1) {
            s += __shfl_xor(s, off);
            ss += __shfl_xor(ss, off);
        }
        int w = tid >> 6, lane = tid & 63;
        if (lane == 0) { sb[w] = s; sb[4 + w] = ss; }
        __syncthreads();
        s = sb[0] + sb[1] + sb[2] + sb[3];
        ss = sb[4] + sb[5] + sb[6] + sb[7];
        float mu = s * (1.0f / DM);
        float var = ss * (1.0f / DM) - mu * mu;
        float rstd = rsqrtf(var + 1e-5f);
        float4 gv = ((const float4*)g)[tid];
        float4 bv = ((const float4*)bt)[tid];
        uint2 hv;
        hv.x = cvtpk((v.x - mu) * rstd * gv.x + bv.x, (v.y - mu) * rstd * gv.y + bv.y);
        hv.y = cvtpk((v.z - mu) * rstd * gv.z + bv.z, (v.w - mu) * rstd * gv.w + bv.w);
        ((uint2*)(H + (size_t)row * DM))[tid] = hv;
    }
}

// ---------------- LayerNorm fp32 -> bf16 (LN2) ----------------
__global__ __launch_bounds__(256) void ln_kernel(const float* __restrict__ X,
                                                 const float* __restrict__ g,
                                                 const float* __restrict__ bt,
                                                 u16* __restrict__ H) {
    int row = blockIdx.x, tid = threadIdx.x;
    float4 v = ((const float4*)(X + (size_t)row * DM))[tid];
    float s = v.x + v.y + v.z + v.w;
    float ss = v.x * v.x + v.y * v.y + v.z * v.z + v.w * v.w;
#pragma unroll
    for (int off = 32; off >= 1; off >>= 1) {
        s += __shfl_xor(s, off);
        ss += __shfl_xor(ss, off);
    }
    __shared__ float sb[8];
    int w = tid >> 6, lane = tid & 63;
    if (lane == 0) { sb[w] = s; sb[4 + w] = ss; }
    __syncthreads();
    s = sb[0] + sb[1] + sb[2] + sb[3];
    ss = sb[4] + sb[5] + sb[6] + sb[7];
    float mu = s * (1.0f / DM);
    float var = ss * (1.0f / DM) - mu * mu;
    float rstd = rsqrtf(var + 1e-5f);
    float4 gv = ((const float4*)g)[tid];
    float4 bv = ((const float4*)bt)[tid];
    uint2 hv;
    hv.x = cvtpk((v.x - mu) * rstd * gv.x + bv.x, (v.y - mu) * rstd * gv.y + bv.y);
    hv.y = cvtpk((v.z - mu) * rstd * gv.z + bv.z, (v.w - mu) * rstd * gv.w + bv.w);
    ((uint2*)(H + (size_t)row * DM))[tid] = hv;
}

// ---------------- out = x1 + b2 + p0 + p1 + p2 + p3 (bf16 partials) ----------------
__global__ __launch_bounds__(256) void add4_kernel(float* __restrict__ out,
                                                   const float* __restrict__ x1,
                                                   const float* __restrict__ b2,
                                                   const u16* __restrict__ p0,
                                                   const u16* __restrict__ p1,
                                                   const u16* __restrict__ p2,
                                                   const u16* __restrict__ p3, int n4) {
    int idx = blockIdx.x * 256 + threadIdx.x;
    const int stride = gridDim.x * 256;
    for (; idx < n4; idx += stride) {
        float4 a = ((const float4*)x1)[idx];
        const float4 bb = ((const float4*)b2)[idx & 255];
        ushort4 c0 = ((const ushort4*)p0)[idx];
        ushort4 c1 = ((const ushort4*)p1)[idx];
        ushort4 c2 = ((const ushort4*)p2)[idx];
        ushort4 c3 = ((const ushort4*)p3)[idx];
        a.x += bb.x + b2f(c0.x) + b2f(c1.x) + b2f(c2.x) + b2f(c3.x);
        a.y += bb.y + b2f(c0.y) + b2f(c1.y) + b2f(c2.y) + b2f(c3.y);
        a.z += bb.z + b2f(c0.z) + b2f(c1.z) + b2f(c2.z) + b2f(c3.z);
        a.w += bb.w + b2f(c0.w) + b2f(c1.w) + b2f(c2.w) + b2f(c3.w);
        ((float4*)out)[idx] = a;
    }
}

// ================= 256x256 8-phase GEMM (T2+T3+T4+T5) =================
// 512 threads = 8 waves (2M x 4N); BK=64; per-wave C = 128x64 (8x4 16x16 frags).
// SPLIT>1: grid y = (M/256)*SPLIT; MODE 3 writes bf16 C-partials pb[ks] (uniform epilogue).
// MODE 0: qkv scatter; MODE 2: gelu(C+bias) bf16; MODE 3: bf16 partial only.
template <int MODE, int SPLIT>
__global__ __launch_bounds__(512, 2) void gemm256(
    const u16* __restrict__ A, const u16* __restrict__ Bt, int M, int N, int K,
    u16* __restrict__ oq, u16* __restrict__ ok, u16* __restrict__ vt,
    const float* __restrict__ bias, u16* __restrict__ outbf,
    u16* __restrict__ pb0, u16* __restrict__ pb1,
    u16* __restrict__ pb2, u16* __restrict__ pb3) {
    __shared__ __align__(16) u16 Alds[2][256][64];
    __shared__ __align__(16) u16 Blds[2][256][64];
    const int tid = threadIdx.x;
    const int lane = tid & 63, w = tid >> 6;
    const int wm = w >> 2, wn = w & 3;
    const int l15 = lane & 15, lg = lane >> 4;
    int bid = blockIdx.x + gridDim.x * blockIdx.y;
    const int nwg = gridDim.x * gridDim.y;
    bid = (bid & 7) * (nwg >> 3) + (bid >> 3);
    int mrow = bid / gridDim.x;
    int ks = 0;
    if constexpr (SPLIT > 1) {
        const int mtiles = (nwg / gridDim.x) / SPLIT;
        ks = mrow / mtiles;
        mrow -= ks * mtiles;
    }
    const int bm = mrow * 256, bn = (bid % gridDim.x) * 256;
    const int kbeg = SPLIT > 1 ? ks * (K / SPLIT) : 0;
    const int srow = tid >> 3, pch = tid & 7;
    const int lc = pch ^ (srow & 7);

    const u16* Ap = A + (size_t)(bm + srow) * K + kbeg + lc * 8;
    const u16* Bp = Bt + (size_t)(bn + srow) * K + kbeg + lc * 8;

    f32x4 acc[8][4] = {};
    bf16x8 bf[4][2];
    const int NT = (K / SPLIT) >> 6;  // even, >= 2

#define SA256(buf, t)                                                           \
    {                                                                           \
        _Pragma("unroll") for (int j = 0; j < 4; ++j)                           \
            gload_lds16(Ap + (size_t)(64 * j) * K + (t) * 64,                   \
                        &Alds[buf][srow + 64 * j][pch * 8]);                    \
    }
#define SB256(buf, t)                                                           \
    {                                                                           \
        _Pragma("unroll") for (int j = 0; j < 4; ++j)                           \
            gload_lds16(Bp + (size_t)(64 * j) * K + (t) * 64,                   \
                        &Blds[buf][srow + 64 * j][pch * 8]);                    \
    }

#define PHASE(BUF, P, STAGE, WAIT)                                              \
    {                                                                           \
        bf16x8 af[2][2];                                                        \
        _Pragma("unroll") for (int i = 0; i < 2; ++i) {                         \
            const int row = wm * 128 + (2 * (P) + i) * 16 + l15;                \
            _Pragma("unroll") for (int ks_ = 0; ks_ < 2; ++ks_)                 \
                af[i][ks_] =                                                    \
                    *(const bf16x8*)&Alds[BUF][row][((ks_ * 4 + lg) ^ (row & 7)) * 8]; \
        }                                                                       \
        if constexpr ((P) == 0) {                                               \
            _Pragma("unroll") for (int nf = 0; nf < 4; ++nf) {                  \
                const int row = wn * 64 + nf * 16 + l15;                        \
                _Pragma("unroll") for (int ks_ = 0; ks_ < 2; ++ks_)             \
                    bf[nf][ks_] =                                               \
                        *(const bf16x8*)&Blds[BUF][row][((ks_ * 4 + lg) ^ (row & 7)) * 8]; \
            }                                                                   \
        }                                                                       \
        STAGE;                                                                  \
        WAIT;                                                                   \
        __builtin_amdgcn_s_barrier();                                           \
        asm volatile("s_waitcnt lgkmcnt(0)" ::: "memory");                      \
        __builtin_amdgcn_sched_barrier(0);                                      \
        __builtin_amdgcn_s_setprio(1);                                          \
        _Pragma("unroll") for (int i = 0; i < 2; ++i)                           \
            _Pragma("unroll") for (int nf = 0; nf < 4; ++nf)                    \
                _Pragma("unroll") for (int ks_ = 0; ks_ < 2; ++ks_)             \
                    acc[2 * (P) + i][nf] =                                      \
                        mfma_bf16(af[i][ks_], bf[nf][ks_], acc[2 * (P) + i][nf]); \
        __builtin_amdgcn_s_setprio(0);                                          \
        __builtin_amdgcn_s_barrier();                                           \
    }

    SB256(0, 0);
    SA256(0, 0);
    SB256(1, 1);
    asm volatile("s_waitcnt vmcnt(4)" ::: "memory");
    __builtin_amdgcn_sched_barrier(0);
    __builtin_amdgcn_s_barrier();

    for (int it = 0; it < (NT >> 1); ++it) {
        const int t0 = 2 * it;
        const bool more = (t0 + 2 < NT);
        PHASE(0, 0, { SA256(1, t0 + 1); }, {});
        PHASE(0, 1, { if (more) SB256(0, t0 + 2); }, {});
        PHASE(0, 2, {}, {});
        PHASE(0, 3, {}, {
            if (more) { asm volatile("s_waitcnt vmcnt(4)" ::: "memory"); }
            else { asm volatile("s_waitcnt vmcnt(0)" ::: "memory"); }
            __builtin_amdgcn_sched_barrier(0);
        });
        PHASE(1, 0, { if (more) SA256(0, t0 + 2); }, {});
        PHASE(1, 1, { if (more) SB256(1, t0 + 3); }, {});
        PHASE(1, 2, {}, {});
        PHASE(1, 3, {}, {
            if (more) {
                asm volatile("s_waitcnt vmcnt(4)" ::: "memory");
                __builtin_amdgcn_sched_barrier(0);
            }
        });
    }
#undef PHASE
#undef SA256
#undef SB256

    const int m0 = bm + wm * 128, n0 = bn + wn * 64;
#pragma unroll
    for (int mi = 0; mi < 8; ++mi) {
#pragma unroll
        for (int ni = 0; ni < 4; ++ni) {
            if constexpr (MODE == 0) {
                const int n = n0 + ni * 16 + l15;
                const int which = n >> 10;
                const int hh = (n >> 6) & 15, d = n & 63;
                const int mbase = m0 + mi * 16 + 4 * lg;
                const int bb = mbase >> 11, t = mbase & 2047;
                if (which == 2) {
                    uint2 pv;
                    pv.x = cvtpk(acc[mi][ni][0], acc[mi][ni][1]);
                    pv.y = cvtpk(acc[mi][ni][2], acc[mi][ni][3]);
                    *(uint2*)(vt + (((size_t)(bb * NH + hh)) * DH + d) * TT + t) = pv;
                } else {
                    u16* dst = which == 0 ? oq : ok;
                    const float sc = which == 0 ? 0.18033688f : 1.0f;  // (1/8)*log2(e)
                    const unsigned p01 = cvtpk(acc[mi][ni][0] * sc, acc[mi][ni][1] * sc);
                    const unsigned p23 = cvtpk(acc[mi][ni][2] * sc, acc[mi][ni][3] * sc);
                    u16* db = dst + (((size_t)(bb * NH + hh)) * TT + t) * DH + d;
                    db[0] = (u16)p01;
                    db[DH] = (u16)(p01 >> 16);
                    db[2 * DH] = (u16)p23;
                    db[3 * DH] = (u16)(p23 >> 16);
                }
            } else if constexpr (MODE == 2) {
                const int n = n0 + ni * 16 + l15;
                const float bn_ = bias[n];
                const float g0 = gelu_fast(acc[mi][ni][0] + bn_);
                const float g1 = gelu_fast(acc[mi][ni][1] + bn_);
                const float g2 = gelu_fast(acc[mi][ni][2] + bn_);
                const float g3 = gelu_fast(acc[mi][ni][3] + bn_);
                const unsigned p01 = cvtpk(g0, g1);
                const unsigned p23 = cvtpk(g2, g3);
                u16* db = outbf + (size_t)(m0 + mi * 16 + 4 * lg) * N + n;
                db[0] = (u16)p01;
                db[N] = (u16)(p01 >> 16);
                db[2 * N] = (u16)p23;
                db[3 * N] = (u16)(p23 >> 16);
            } else {  // MODE 3: uniform bf16 C-partial (resid+bias folded into add4)
                const int n = n0 + ni * 16 + l15;
                u16* pb = ks == 0 ? pb0 : (ks == 1 ? pb1 : (ks == 2 ? pb2 : pb3));
                const unsigned q01 = cvtpk(acc[mi][ni][0], acc[mi][ni][1]);
                const unsigned q23 = cvtpk(acc[mi][ni][2], acc[mi][ni][3]);
                u16* db = pb + (size_t)(m0 + mi * 16 + 4 * lg) * N + n;
                db[0] = (u16)q01;
                db[N] = (u16)(q01 >> 16);
                db[2 * N] = (u16)q23;
                db[3 * N] = (u16)(q23 >> 16);
            }
        }
    }
}

// ---------------- 128x128 bf16 MFMA GEMM (wout) ----------------
template <int MODE>
__global__ __launch_bounds__(256) void gemm_kernel(
    const u16* __restrict__ A, const u16* __restrict__ Bt, int M, int N, int K,
    const float* __restrict__ resid, float* __restrict__ outf,
    const float* __restrict__ bias) {
    __shared__ __align__(16) u16 Alds[2][128][64];
    __shared__ __align__(16) u16 Blds[2][128][64];
    const int tid = threadIdx.x;
    const int lane = tid & 63;
    const int w = tid >> 6;
    const int wr = w >> 1, wc = w & 1;
    int bid = blockIdx.x + gridDim.x * blockIdx.y;
    const int nwg = gridDim.x * gridDim.y;
    bid = (bid & 7) * (nwg >> 3) + (bid >> 3);
    const int bm = (bid / gridDim.x) * 128, bn = (bid % gridDim.x) * 128;
    const int l15 = lane & 15, lg = lane >> 4;
    const int srow = tid >> 3, pch = tid & 7;
    const int lc = pch ^ (srow & 7);

    f32x4 acc[4][4] = {};
    const u16* Ap = A + (size_t)(bm + srow) * K + lc * 8;
    const u16* Bp = Bt + (size_t)(bn + srow) * K + lc * 8;

#define STAGE(buf, k0)                                                          \
    {                                                                           \
        _Pragma("unroll") for (int i = 0; i < 4; ++i) {                         \
            gload_lds16(Ap + (size_t)(32 * i) * K + (k0), &Alds[buf][srow + 32 * i][pch * 8]); \
            gload_lds16(Bp + (size_t)(32 * i) * K + (k0), &Blds[buf][srow + 32 * i][pch * 8]); \
        }                                                                       \
    }

#define COMPUTE(buf)                                                            \
    {                                                                           \
        _Pragma("unroll") for (int kk = 0; kk < 2; ++kk) {                      \
            bf16x8 af[4], bfr[4];                                               \
            _Pragma("unroll") for (int f = 0; f < 4; ++f) {                     \
                const int ar = wr * 64 + f * 16 + l15;                          \
                const int br = wc * 64 + f * 16 + l15;                          \
                const int kch = kk * 4 + lg;                                    \
                af[f] = *(const bf16x8*)&Alds[buf][ar][(kch ^ (ar & 7)) * 8];   \
                bfr[f] = *(const bf16x8*)&Blds[buf][br][(kch ^ (br & 7)) * 8];  \
            }                                                                   \
            _Pragma("unroll") for (int mi = 0; mi < 4; ++mi)                    \
                _Pragma("unroll") for (int ni = 0; ni < 4; ++ni)                \
                    acc[mi][ni] = mfma_bf16(af[mi], bfr[ni], acc[mi][ni]);      \
        }                                                                       \
    }

    STAGE(0, 0);
    for (int k0 = 0; k0 < K; k0 += 64) {
        const int cur = (k0 >> 6) & 1;
        if (k0 + 64 < K) {
            STAGE(cur ^ 1, k0 + 64);
            asm volatile("s_waitcnt vmcnt(8)" ::: "memory");
        } else {
            asm volatile("s_waitcnt vmcnt(0)" ::: "memory");
        }
        __builtin_amdgcn_sched_barrier(0);
        __builtin_amdgcn_s_barrier();
        __builtin_amdgcn_sched_barrier(0);
        COMPUTE(cur);
        __builtin_amdgcn_s_barrier();
    }
#undef STAGE
#undef COMPUTE

    const int m0 = bm + wr * 64, n0 = bn + wc * 64;
#pragma unroll
    for (int mi = 0; mi < 4; ++mi) {
#pragma unroll
        for (int ni = 0; ni < 4; ++ni) {
            const int n = n0 + ni * 16 + l15;
#pragma unroll
            for (int r = 0; r < 4; ++r) {
                const int m = m0 + mi * 16 + 4 * lg + r;
                const float v = acc[mi][ni][r];
                const size_t o = (size_t)m * N + n;
                if constexpr (MODE == 1) {
                    outf[o] = resid[o] + v;
                } else {
                    outf[o] = resid[o] + v + bias[n];
                }
            }
        }
    }
}

// ---------------- flash attention, causal, swapped-operand MFMA ----------------
// Zero-shuffle PV: k-axis of PV permuted by sigma(k)=[kf|j2|lg|j1j0] on BOTH operands;
// P B-fragments = lane-local pk concatenation (no cross-lane ops); V read as 2x8B halves.
__global__ __launch_bounds__(256) void attn_kernel(const u16* __restrict__ Q,
                                                   const u16* __restrict__ Kg,
                                                   const u16* __restrict__ Vtg,
                                                   u16* __restrict__ O) {
    __shared__ __align__(16) u16 Klds[4][64][64];
    __shared__ __align__(16) u16 Vlds[4][64][64];
    const int tid = threadIdx.x, lane = tid & 63, w = tid >> 6;
    const int l15 = lane & 15, lg = lane >> 4;

    int id = blockIdx.x + (blockIdx.y << 4);
    int sw = (id & 7) * 64 + (id >> 3);  // XCD k -> heads 4k..4k+3
    const int p = sw & 15, bh = sw >> 4;
    const size_t base = (size_t)bh * TT * DH;
    const int b = bh >> 4, hh = bh & 15;

    const int srow = tid >> 3, pch = tid & 7;
    const int lc = pch ^ (srow & 7);

    const int vhalf = (lg & 1) * 8;   // byte offset of the 4-elem half within a 16B chunk
    const int vc = lg >> 1;           // base chunk (0 or 1)

#define ASTAGE(buf, kv)                                                                     \
    {                                                                                       \
        gload_lds16(Kg + base + (size_t)((kv) * 64 + srow) * DH + lc * 8,                   \
                    &Klds[buf][srow][pch * 8]);                                             \
        gload_lds16(Kg + base + (size_t)((kv) * 64 + srow + 32) * DH + lc * 8,              \
                    &Klds[buf][srow + 32][pch * 8]);                                        \
        gload_lds16(Vtg + base + (size_t)srow * TT + (kv) * 64 + lc * 8,                    \
                    &Vlds[buf][srow][pch * 8]);                                             \
        gload_lds16(Vtg + base + (size_t)(srow + 32) * TT + (kv) * 64 + lc * 8,             \
                    &Vlds[buf][srow + 32][pch * 8]);                                        \
    }

    for (int half = 0; half < 2; ++half) {
        const int qt = half ? (31 - p) : p;
        const int nkv = qt + 1;
        const int qrow = qt * 64 + w * 16 + l15;
        uint4 qu0 = *(const uint4*)(Q + base + (size_t)qrow * DH + 8 * lg);
        uint4 qu1 = *(const uint4*)(Q + base + (size_t)qrow * DH + 32 + 8 * lg);
        asm volatile("" : "+v"(qu0.x), "+v"(qu0.y), "+v"(qu0.z), "+v"(qu0.w),
                          "+v"(qu1.x), "+v"(qu1.y), "+v"(qu1.z), "+v"(qu1.w));
        const bf16x8 qf0 = *(const bf16x8*)&qu0;
        const bf16x8 qf1 = *(const bf16x8*)&qu1;

        f32x4 o[4] = {};
        float lsum = 0.0f;

        auto compute_tile = [&](int buf, bool masked, int kvi) {
            // S^T = K Q^T
            f32x4 s[4] = {};
            __builtin_amdgcn_s_setprio(1);
#pragma unroll
            for (int nf = 0; nf < 4; ++nf) {
                const int row = nf * 16 + l15;
                bf16x8 kb0 = *(const bf16x8*)&Klds[buf][row][(lg ^ (l15 & 7)) * 8];
                bf16x8 kb1 = *(const bf16x8*)&Klds[buf][row][((4 + lg) ^ (l15 & 7)) * 8];
                s[nf] = mfma_bf16(kb0, qf0, s[nf]);
                s[nf] = mfma_bf16(kb1, qf1, s[nf]);
            }
            __builtin_amdgcn_s_setprio(0);

            if (masked) {
#pragma unroll
                for (int nf = 0; nf < 4; ++nf) {
                    const int tg = kvi * 64 + nf * 16 + 4 * lg;
#pragma unroll
                    for (int r = 0; r < 4; ++r)
                        if (tg + r > qrow) s[nf][r] = -1e30f;
                }
            }

            // fixed-reference softmax: P = exp2(S') directly
            float ps = 0.0f;
#pragma unroll
            for (int nf = 0; nf < 4; ++nf) {
#pragma unroll
                for (int r = 0; r < 4; ++r) {
                    const float pp = exp2f(s[nf][r]);
                    s[nf][r] = pp;
                    ps += pp;
                }
            }
            lsum += ps;

            // pack P rows to bf16; under sigma, pa = lane-local concatenation (no shuffles)
            unsigned pk[4][2];
#pragma unroll
            for (int nf = 0; nf < 4; ++nf) {
                pk[nf][0] = cvtpk(s[nf][0], s[nf][1]);
                pk[nf][1] = cvtpk(s[nf][2], s[nf][3]);
            }
            uint4 pu0, pu1;
            pu0.x = pk[0][0]; pu0.y = pk[0][1]; pu0.z = pk[1][0]; pu0.w = pk[1][1];
            pu1.x = pk[2][0]; pu1.y = pk[2][1]; pu1.z = pk[3][0]; pu1.w = pk[3][1];
            const bf16x8 pa0 = *(const bf16x8*)&pu0;
            const bf16x8 pa1 = *(const bf16x8*)&pu1;

            // O^T += V^T P^T  (V columns read sigma-permuted: two 8B halves per fragment)
            __builtin_amdgcn_s_setprio(1);
#pragma unroll
            for (int nf = 0; nf < 4; ++nf) {
                const int row = nf * 16 + l15;
                const int swz = row & 7;
                const char* vb = (const char*)&Vlds[buf][row][0];
                uint2 a0 = *(const uint2*)(vb + (((vc + 0) ^ swz) * 16 + vhalf));
                uint2 a1 = *(const uint2*)(vb + (((vc + 2) ^ swz) * 16 + vhalf));
                uint2 b0 = *(const uint2*)(vb + (((vc + 4) ^ swz) * 16 + vhalf));
                uint2 b1 = *(const uint2*)(vb + (((vc + 6) ^ swz) * 16 + vhalf));
                uint4 v0; v0.x = a0.x; v0.y = a0.y; v0.z = a1.x; v0.w = a1.y;
                uint4 v1; v1.x = b0.x; v1.y = b0.y; v1.z = b1.x; v1.w = b1.y;
                o[nf] = mfma_bf16(*(const bf16x8*)&v0, pa0, o[nf]);
                o[nf] = mfma_bf16(*(const bf16x8*)&v1, pa1, o[nf]);
            }
            __builtin_amdgcn_s_setprio(0);
        };

        ASTAGE(0, 0);
        if (nkv > 1) ASTAGE(1, 1);

        for (int kv = 0; kv < nkv; kv += 2) {
            int nst = 0;
            if (kv + 2 < nkv) { ASTAGE((kv + 2) & 3, kv + 2); nst += 4; }
            if (kv + 3 < nkv) { ASTAGE((kv + 3) & 3, kv + 3); nst += 4; }
            if (nst == 8)
                asm volatile("s_waitcnt vmcnt(8)" ::: "memory");
            else if (nst == 4)
                asm volatile("s_waitcnt vmcnt(4)" ::: "memory");
            else
                asm volatile("s_waitcnt vmcnt(0)" ::: "memory");
            __builtin_amdgcn_sched_barrier(0);
            __builtin_amdgcn_s_barrier();
            __builtin_amdgcn_sched_barrier(0);

            compute_tile(kv & 3, kv == qt, kv);
            if (kv + 1 < nkv) compute_tile((kv + 1) & 3, kv + 1 == qt, kv + 1);

            __builtin_amdgcn_s_barrier();
        }

        lsum += __shfl_xor(lsum, 16);
        lsum += __shfl_xor(lsum, 32);
        const float linv = 1.0f / lsum;
#pragma unroll
        for (int nf = 0; nf < 4; ++nf) {
            uint2 pv;
            pv.x = cvtpk(o[nf][0] * linv, o[nf][1] * linv);
            pv.y = cvtpk(o[nf][2] * linv, o[nf][3] * linv);
            *(uint2*)(O + ((size_t)b * TT + qrow) * DM + hh * DH + nf * 16 + 4 * lg) = pv;
        }
    }
#undef ASTAGE
}

extern "C" void kernel_launch(void* const* d_in, const int* in_sizes, int n_in,
                              void* d_out, int out_size, void* d_ws, size_t ws_size,
                              hipStream_t stream) {
    const float* x = (const float*)d_in[0];
    const float* wqkv = (const float*)d_in[1];
    const float* wout = (const float*)d_in[2];
    const float* ln1g = (const float*)d_in[3];
    const float* ln1b = (const float*)d_in[4];
    const float* ln2g = (const float*)d_in[5];
    const float* ln2b = (const float*)d_in[6];
    const float* w1 = (const float*)d_in[7];
    const float* b1 = (const float*)d_in[8];
    const float* w2 = (const float*)d_in[9];
    const float* b2 = (const float*)d_in[10];
    float* out = (float*)d_out;
    char* ws = (char*)d_ws;

    u16* wqkv_t = (u16*)(ws + 0);          // [3072][1024] bf16 (dead by FF2)
    u16* wout_t = (u16*)(ws + 6291456);    // [1024][1024]      (dead by FF2)
    u16* w1_t   = (u16*)(ws + 8388608);    // [4096][1024]      (dead by FF2)
    u16* w2_t   = (u16*)(ws + 16777216);   // [1024][4096]
    u16* h_bf   = (u16*)(ws + 25165824);   // [4096][1024] (LN1/LN2; dead by FF2)
    u16* q_bf   = (u16*)(ws + 33554432);   // [B,H,T,Dh]
    u16* k_bf   = (u16*)(ws + 41943040);   // [B,H,T,Dh]
    u16* vt_bf  = (u16*)(ws + 50331648);   // [B,H,Dh,T]  (V^T)
    u16* at_bf  = (u16*)(ws + 58720256);   // [4096][1024] (dead by FF2)
    float* x1   = (float*)(ws + 67108864); // [4096][1024] fp32
    u16* ff1_bf = q_bf;                    // aliases q/k/vt (dead by FF1): [4096][4096]
    // FF2 bf16 K-quarter partials (regions dead by FF2 time):
    u16* pb0 = (u16*)(ws + 58720256);      // 8 MB (over at_bf)
    u16* pb1 = (u16*)(ws + 0);             // 8 MB (over wqkv_t+wout_t)
    u16* pb2 = (u16*)(ws + 8388608);       // 8 MB (over w1_t)
    u16* pb3 = (u16*)(ws + 25165824);      // 8 MB (over h_bf)

    // fused: 4x weight transpose + LN1
    prep_kernel<<<16384, 256, 0, stream>>>(wqkv, wout, w1, w2,
                                           wqkv_t, wout_t, w1_t, w2_t,
                                           x, ln1g, ln1b, h_bf);

    gemm256<0, 1><<<dim3(12, 16), 512, 0, stream>>>(h_bf, wqkv_t, 4096, 3072, 1024,
                                                    q_bf, k_bf, vt_bf, nullptr, nullptr,
                                                    nullptr, nullptr, nullptr, nullptr);

    attn_kernel<<<dim3(16, 32), 256, 0, stream>>>(q_bf, k_bf, vt_bf, at_bf);

    gemm_kernel<1><<<dim3(8, 32), 256, 0, stream>>>(at_bf, wout_t, 4096, 1024, 1024,
                                                    x, x1, nullptr);

    ln_kernel<<<4096, 256, 0, stream>>>(x1, ln2g, ln2b, h_bf);

    gemm256<2, 1><<<dim3(16, 16), 512, 0, stream>>>(h_bf, w1_t, 4096, 4096, 1024,
                                                    nullptr, nullptr, nullptr, b1, ff1_bf,
                                                    nullptr, nullptr, nullptr, nullptr);

    // FF2: 256^2 8-phase, split-K 4 -> 256 blocks (1/CU), uniform bf16-partial epilogue
    gemm256<3, 4><<<dim3(4, 64), 512, 0, stream>>>(ff1_bf, w2_t, 4096, 1024, 4096,
                                                   nullptr, nullptr, nullptr, nullptr, nullptr,
                                                   pb0, pb1, pb2, pb3);

    // out = x1 + b2 + sum of partials
    add4_kernel<<<2048, 256, 0, stream>>>(out, x1, b2, pb0, pb1, pb2, pb3,
                                          4096 * 1024 / 4);
}